// Round 6
// baseline (463.586 us; speedup 1.0000x reference)
//
#include <hip/hip_runtime.h>
#include <hip/hip_bf16.h>

#define N_NODES 100000
#define N_EDGES 3200000
#define N_GRAPHS 64
#define NB 391                 // dst-buckets of 256 nodes (last has 160)
#define KCH 8192               // edges per binning block
#define NCHUNK ((N_EDGES + KCH - 1) / KCH)   // 391
#define MAXBKT 10240           // passB staging capacity (mean 8192, sigma ~90)
#define NBLK3 (N_NODES / 32)   // 3125 fused-L3 blocks

__device__ __forceinline__ void atomAddF(float* p, float v) {
    unsafeAtomicAdd(p, v);
}

// bf16x2 pack/unpack (RTNE via __float2bfloat16)
__device__ __forceinline__ float lo2f(unsigned u) { return __uint_as_float(u << 16); }
__device__ __forceinline__ float hi2f(unsigned u) { return __uint_as_float(u & 0xFFFF0000u); }
__device__ __forceinline__ unsigned pack2(float a, float b) {
    unsigned ha = __bfloat16_as_ushort(__float2bfloat16(a));
    unsigned hb = __bfloat16_as_ushort(__float2bfloat16(b));
    return ha | (hb << 16);
}

// ---------------- CSR build: two-level binning ----------------
__global__ __launch_bounds__(512) void k_binCount(const int* __restrict__ dst,
                                                  int* __restrict__ gcount) {
    __shared__ int hist[NB];
    for (int t = threadIdx.x; t < NB; t += 512) hist[t] = 0;
    __syncthreads();
    int base = blockIdx.x * KCH;
    int cnt = min(KCH, N_EDGES - base);
    for (int i = threadIdx.x; i < cnt; i += 512)
        atomicAdd(&hist[dst[base + i] >> 8], 1);
    __syncthreads();
    for (int t = threadIdx.x; t < NB; t += 512)
        if (hist[t]) atomicAdd(&gcount[t], hist[t]);
}

__global__ __launch_bounds__(512) void k_scanB(const int* __restrict__ gcount,
                                               int* __restrict__ gbase,
                                               int* __restrict__ gcursor,
                                               int* __restrict__ rowptr) {
    __shared__ int s[512];
    int v = (threadIdx.x < NB) ? gcount[threadIdx.x] : 0;
    s[threadIdx.x] = v;
    __syncthreads();
    for (int off = 1; off < 512; off <<= 1) {
        int t = (threadIdx.x >= off) ? s[threadIdx.x - off] : 0;
        __syncthreads();
        s[threadIdx.x] += t;
        __syncthreads();
    }
    if (threadIdx.x < NB) {
        int e = s[threadIdx.x] - v;
        gbase[threadIdx.x] = e;
        gcursor[threadIdx.x] = e;
    }
    if (threadIdx.x == 0) rowptr[N_NODES] = N_EDGES;
}

// binA v2: STATIC per-thread arrays (rule #20: runtime-indexed arrays -> scratch),
// no LDS staging, no prefix scan, no binary search. Per-bucket block reservation
// (one global atomic per non-empty bucket) + direct dword scatter (L2 absorbs).
__global__ __launch_bounds__(512) void k_binA(const int* __restrict__ src,
                                              const int* __restrict__ dst,
                                              int* __restrict__ gcursor,
                                              int* __restrict__ binned) {
    __shared__ int hist[512];
    __shared__ int rbase[512];
    hist[threadIdx.x] = 0;
    __syncthreads();
    int base = blockIdx.x * KCH;
    int cnt = min(KCH, N_EDGES - base);
    int pk[16];    // packed (dst&255)<<24 | src
    int meta[16];  // (b<<13) | pos, or -1
    #pragma unroll
    for (int i = 0; i < 16; ++i) {
        int idx = i * 512 + threadIdx.x;
        if (idx < cnt) {
            int d = dst[base + idx];
            int b = d >> 8;
            int pos = atomicAdd(&hist[b], 1);        // pos < 8192 -> 13 bits
            pk[i] = ((d & 255) << 24) | src[base + idx];
            meta[i] = (b << 13) | pos;
        } else {
            meta[i] = -1;
        }
    }
    __syncthreads();
    if (threadIdx.x < NB) {
        int v = hist[threadIdx.x];
        if (v > 0) rbase[threadIdx.x] = atomicAdd(&gcursor[threadIdx.x], v);
    }
    __syncthreads();
    #pragma unroll
    for (int i = 0; i < 16; ++i) {
        if (meta[i] >= 0) {
            int b = meta[i] >> 13;
            int pos = meta[i] & 8191;
            binned[rbase[b] + pos] = pk[i];
        }
    }
}

__global__ __launch_bounds__(512) void k_passB(const int* __restrict__ gbase,
                                               int* __restrict__ csr,
                                               int* __restrict__ rowptr,
                                               float* __restrict__ dinv) {
    int b = blockIdx.x;
    int rb = gbase[b];
    int re = (b == NB - 1) ? N_EDGES : gbase[b + 1];
    int cnt = re - rb;
    int nbase = b << 8;
    int nn = min(nbase + 256, N_NODES) - nbase;
    __shared__ int stage[MAXBKT];   // 40 KB
    __shared__ int nhist[256];
    __shared__ int sc[256];
    __shared__ int ncur[256];
    for (int t = threadIdx.x; t < 256; t += 512) nhist[t] = 0;
    __syncthreads();
    for (int j = threadIdx.x; j < cnt; j += 512) {
        int p = csr[rb + j];
        stage[j] = p;
        atomicAdd(&nhist[((unsigned)p) >> 24], 1);
    }
    __syncthreads();
    if (threadIdx.x < 256) sc[threadIdx.x] = nhist[threadIdx.x];
    __syncthreads();
    for (int off = 1; off < 256; off <<= 1) {
        int t = (threadIdx.x < 256 && threadIdx.x >= off) ? sc[threadIdx.x - off] : 0;
        __syncthreads();
        if (threadIdx.x < 256) sc[threadIdx.x] += t;
        __syncthreads();
    }
    if (threadIdx.x < 256) {
        int e = sc[threadIdx.x] - nhist[threadIdx.x];
        ncur[threadIdx.x] = e;
        if (threadIdx.x < nn) {
            rowptr[nbase + threadIdx.x] = rb + e;
            dinv[nbase + threadIdx.x] = rsqrtf((float)nhist[threadIdx.x] + 1.0f);
        }
    }
    __syncthreads();
    for (int j = threadIdx.x; j < cnt; j += 512) {
        int p = stage[j];
        int slot = atomicAdd(&ncur[((unsigned)p) >> 24], 1);
        csr[rb + slot] = p;
    }
}

// -------- gather: out = di*(sum A'[s] + A'[n]) (+bias,relu) --------
// Features pre-scaled by dinv (A'[u] = dinv[u]*h[u]) => no per-edge dinv/coef.
// uint4 loads (16 B/lane = 8 bf16) + 8-way unrolled edge loop.
template<int LOGW, bool BIAS_RELU, bool OB, bool PRE>
__global__ void __launch_bounds__(256) k_gatherB(
        const int* __restrict__ rowptr, const int* __restrict__ csr,
        const unsigned* __restrict__ in /* bf16x2 pairs, prescaled */,
        const float* __restrict__ dinv,
        const float* __restrict__ ba, const float* __restrict__ bb,
        void* __restrict__ out) {
    constexpr int W8 = (1 << LOGW) / 8;   // lanes per node (uint4 = 8 bf16)
    constexpr int NPB = 256 / W8;         // nodes per block
    int n = blockIdx.x * NPB + (threadIdx.x / W8);
    if (n >= N_NODES) return;
    int sub = threadIdx.x % W8;
    const uint4* in4 = (const uint4*)in;
    uint4 u = in4[(size_t)n * W8 + sub];              // self term A'[n]
    float a0 = lo2f(u.x), a1 = hi2f(u.x), a2 = lo2f(u.y), a3 = hi2f(u.y);
    float a4 = lo2f(u.z), a5 = hi2f(u.z), a6 = lo2f(u.w), a7 = hi2f(u.w);
    int j = rowptr[n], end = rowptr[n + 1];
    for (; j + 8 <= end; j += 8) {
        int s0 = csr[j] & 0xFFFFFF;
        int s1 = csr[j + 1] & 0xFFFFFF;
        int s2 = csr[j + 2] & 0xFFFFFF;
        int s3 = csr[j + 3] & 0xFFFFFF;
        int s4 = csr[j + 4] & 0xFFFFFF;
        int s5 = csr[j + 5] & 0xFFFFFF;
        int s6 = csr[j + 6] & 0xFFFFFF;
        int s7 = csr[j + 7] & 0xFFFFFF;
        uint4 v0 = in4[(size_t)s0 * W8 + sub];
        uint4 v1 = in4[(size_t)s1 * W8 + sub];
        uint4 v2 = in4[(size_t)s2 * W8 + sub];
        uint4 v3 = in4[(size_t)s3 * W8 + sub];
        uint4 v4 = in4[(size_t)s4 * W8 + sub];
        uint4 v5 = in4[(size_t)s5 * W8 + sub];
        uint4 v6 = in4[(size_t)s6 * W8 + sub];
        uint4 v7 = in4[(size_t)s7 * W8 + sub];
        a0 += ((lo2f(v0.x) + lo2f(v1.x)) + (lo2f(v2.x) + lo2f(v3.x)))
            + ((lo2f(v4.x) + lo2f(v5.x)) + (lo2f(v6.x) + lo2f(v7.x)));
        a1 += ((hi2f(v0.x) + hi2f(v1.x)) + (hi2f(v2.x) + hi2f(v3.x)))
            + ((hi2f(v4.x) + hi2f(v5.x)) + (hi2f(v6.x) + hi2f(v7.x)));
        a2 += ((lo2f(v0.y) + lo2f(v1.y)) + (lo2f(v2.y) + lo2f(v3.y)))
            + ((lo2f(v4.y) + lo2f(v5.y)) + (lo2f(v6.y) + lo2f(v7.y)));
        a3 += ((hi2f(v0.y) + hi2f(v1.y)) + (hi2f(v2.y) + hi2f(v3.y)))
            + ((hi2f(v4.y) + hi2f(v5.y)) + (hi2f(v6.y) + hi2f(v7.y)));
        a4 += ((lo2f(v0.z) + lo2f(v1.z)) + (lo2f(v2.z) + lo2f(v3.z)))
            + ((lo2f(v4.z) + lo2f(v5.z)) + (lo2f(v6.z) + lo2f(v7.z)));
        a5 += ((hi2f(v0.z) + hi2f(v1.z)) + (hi2f(v2.z) + hi2f(v3.z)))
            + ((hi2f(v4.z) + hi2f(v5.z)) + (hi2f(v6.z) + hi2f(v7.z)));
        a6 += ((lo2f(v0.w) + lo2f(v1.w)) + (lo2f(v2.w) + lo2f(v3.w)))
            + ((lo2f(v4.w) + lo2f(v5.w)) + (lo2f(v6.w) + lo2f(v7.w)));
        a7 += ((hi2f(v0.w) + hi2f(v1.w)) + (hi2f(v2.w) + hi2f(v3.w)))
            + ((hi2f(v4.w) + hi2f(v5.w)) + (hi2f(v6.w) + hi2f(v7.w)));
    }
    for (; j < end; ++j) {
        int s = csr[j] & 0xFFFFFF;
        uint4 v = in4[(size_t)s * W8 + sub];
        a0 += lo2f(v.x); a1 += hi2f(v.x);
        a2 += lo2f(v.y); a3 += hi2f(v.y);
        a4 += lo2f(v.z); a5 += hi2f(v.z);
        a6 += lo2f(v.w); a7 += hi2f(v.w);
    }
    float di = dinv[n];
    a0 *= di; a1 *= di; a2 *= di; a3 *= di;
    a4 *= di; a5 *= di; a6 *= di; a7 *= di;
    if (BIAS_RELU) {
        constexpr int H = (1 << LOGW) / 2;
        int d = sub * 8;                 // 8 | H for all instantiations
        const float* bp = (d < H) ? (ba + d) : (bb + d - H);
        a0 = fmaxf(a0 + bp[0], 0.0f);
        a1 = fmaxf(a1 + bp[1], 0.0f);
        a2 = fmaxf(a2 + bp[2], 0.0f);
        a3 = fmaxf(a3 + bp[3], 0.0f);
        a4 = fmaxf(a4 + bp[4], 0.0f);
        a5 = fmaxf(a5 + bp[5], 0.0f);
        a6 = fmaxf(a6 + bp[6], 0.0f);
        a7 = fmaxf(a7 + bp[7], 0.0f);
    }
    if (PRE) {  // pre-scale for the NEXT gather layer
        a0 *= di; a1 *= di; a2 *= di; a3 *= di;
        a4 *= di; a5 *= di; a6 *= di; a7 *= di;
    }
    if (OB) {
        ((uint4*)out)[(size_t)n * W8 + sub] =
            make_uint4(pack2(a0, a1), pack2(a2, a3), pack2(a4, a5), pack2(a6, a7));
    } else {
        constexpr int OUT4 = (1 << LOGW) / 4;
        float4* o4 = (float4*)out;
        o4[(size_t)n * OUT4 + sub * 2]     = make_float4(a0, a1, a2, a3);
        o4[(size_t)n * OUT4 + sub * 2 + 1] = make_float4(a4, a5, a6, a7);
    }
}

#define FMA4(A, W) \
    A.x = fmaf(r, W.x, A.x); A.y = fmaf(r, W.y, A.y); \
    A.z = fmaf(r, W.z, A.z); A.w = fmaf(r, W.w, A.w);

// ======== fused L3: gather(w64) + dense(32->64 x2, bias+relu) + pool-partials ========
// Block = 256 threads = 32 nodes x 8 lanes. STATIC register indexing only.
// Weight chunks padded 16->20 floats: per-q reads hit bank groups 4*(5q+t4) mod 32
// (5q mod 8 is a permutation) -> conflict-free with static access order.
// boff: block-index offset (kernel launched as two half-grids for profiler tiering).
__global__ void __launch_bounds__(256) k_gd3(
        const int* __restrict__ rowptr, const int* __restrict__ csr,
        const unsigned* __restrict__ in,     // B: bf16x2, dinv-prescaled, 64 dims
        const float* __restrict__ dinv,
        const float* __restrict__ W3m, const float* __restrict__ b3m,
        const float* __restrict__ W3l, const float* __restrict__ b3l,
        const int* __restrict__ batch,
        float* __restrict__ part0, float* __restrict__ part1,
        int* __restrict__ pg0, int* __restrict__ pg1, int boff) {
    __shared__ float s_ali[32 * 160];     // 20.5 KB: sWall (p2) / h3s (p3)
    __shared__ float agg[32 * 68];        // 8.7 KB
    __shared__ float sbias[128];
    __shared__ int   sbatch[32];
    __shared__ int   ssplit;
    float* sWall = s_ali;                 // [32 k][chunk q: q*20 + 0..15]
    float* h3s   = s_ali;                 // [32 n][132]

    int blk = blockIdx.x + boff;
    // stage weights (chunk-padded), biases, batch
    for (int t = threadIdx.x; t < 4096; t += 256) {
        int k = t >> 7, D = t & 127;
        float wv = (D < 64) ? W3m[k * 64 + D] : W3l[k * 64 + (D - 64)];
        sWall[k * 160 + (D >> 4) * 20 + (D & 15)] = wv;
    }
    if (threadIdx.x < 128)
        sbias[threadIdx.x] = (threadIdx.x < 64) ? b3m[threadIdx.x]
                                                : b3l[threadIdx.x - 64];
    int nbase = blk * 32;
    if (threadIdx.x < 32) sbatch[threadIdx.x] = batch[nbase + threadIdx.x];

    // ---- phase 1: gather (identical math to k_gatherB<6,false,*,false>) ----
    int ln  = threadIdx.x >> 3;
    int sub = threadIdx.x & 7;
    int n = nbase + ln;
    const uint4* in4 = (const uint4*)in;
    uint4 u = in4[(size_t)n * 8 + sub];
    float a0 = lo2f(u.x), a1 = hi2f(u.x), a2 = lo2f(u.y), a3 = hi2f(u.y);
    float a4 = lo2f(u.z), a5 = hi2f(u.z), a6 = lo2f(u.w), a7 = hi2f(u.w);
    int j = rowptr[n], end = rowptr[n + 1];
    for (; j + 8 <= end; j += 8) {
        int s0 = csr[j] & 0xFFFFFF;
        int s1 = csr[j + 1] & 0xFFFFFF;
        int s2 = csr[j + 2] & 0xFFFFFF;
        int s3 = csr[j + 3] & 0xFFFFFF;
        int s4 = csr[j + 4] & 0xFFFFFF;
        int s5 = csr[j + 5] & 0xFFFFFF;
        int s6 = csr[j + 6] & 0xFFFFFF;
        int s7 = csr[j + 7] & 0xFFFFFF;
        uint4 v0 = in4[(size_t)s0 * 8 + sub];
        uint4 v1 = in4[(size_t)s1 * 8 + sub];
        uint4 v2 = in4[(size_t)s2 * 8 + sub];
        uint4 v3 = in4[(size_t)s3 * 8 + sub];
        uint4 v4 = in4[(size_t)s4 * 8 + sub];
        uint4 v5 = in4[(size_t)s5 * 8 + sub];
        uint4 v6 = in4[(size_t)s6 * 8 + sub];
        uint4 v7 = in4[(size_t)s7 * 8 + sub];
        a0 += ((lo2f(v0.x) + lo2f(v1.x)) + (lo2f(v2.x) + lo2f(v3.x)))
            + ((lo2f(v4.x) + lo2f(v5.x)) + (lo2f(v6.x) + lo2f(v7.x)));
        a1 += ((hi2f(v0.x) + hi2f(v1.x)) + (hi2f(v2.x) + hi2f(v3.x)))
            + ((hi2f(v4.x) + hi2f(v5.x)) + (hi2f(v6.x) + hi2f(v7.x)));
        a2 += ((lo2f(v0.y) + lo2f(v1.y)) + (lo2f(v2.y) + lo2f(v3.y)))
            + ((lo2f(v4.y) + lo2f(v5.y)) + (lo2f(v6.y) + lo2f(v7.y)));
        a3 += ((hi2f(v0.y) + hi2f(v1.y)) + (hi2f(v2.y) + hi2f(v3.y)))
            + ((hi2f(v4.y) + hi2f(v5.y)) + (hi2f(v6.y) + hi2f(v7.y)));
        a4 += ((lo2f(v0.z) + lo2f(v1.z)) + (lo2f(v2.z) + lo2f(v3.z)))
            + ((lo2f(v4.z) + lo2f(v5.z)) + (lo2f(v6.z) + lo2f(v7.z)));
        a5 += ((hi2f(v0.z) + hi2f(v1.z)) + (hi2f(v2.z) + hi2f(v3.z)))
            + ((hi2f(v4.z) + hi2f(v5.z)) + (hi2f(v6.z) + hi2f(v7.z)));
        a6 += ((lo2f(v0.w) + lo2f(v1.w)) + (lo2f(v2.w) + lo2f(v3.w)))
            + ((lo2f(v4.w) + lo2f(v5.w)) + (lo2f(v6.w) + lo2f(v7.w)));
        a7 += ((hi2f(v0.w) + hi2f(v1.w)) + (hi2f(v2.w) + hi2f(v3.w)))
            + ((hi2f(v4.w) + hi2f(v5.w)) + (hi2f(v6.w) + hi2f(v7.w)));
    }
    for (; j < end; ++j) {
        int s = csr[j] & 0xFFFFFF;
        uint4 v = in4[(size_t)s * 8 + sub];
        a0 += lo2f(v.x); a1 += hi2f(v.x);
        a2 += lo2f(v.y); a3 += hi2f(v.y);
        a4 += lo2f(v.z); a5 += hi2f(v.z);
        a6 += lo2f(v.w); a7 += hi2f(v.w);
    }
    float di = dinv[n];
    a0 *= di; a1 *= di; a2 *= di; a3 *= di;
    a4 *= di; a5 *= di; a6 *= di; a7 *= di;
    {
        float* ap = &agg[ln * 68 + sub * 8];
        *(float4*)&ap[0] = make_float4(a0, a1, a2, a3);
        *(float4*)&ap[4] = make_float4(a4, a5, a6, a7);
    }
    if (threadIdx.x == 0) {               // segment split (<=2 graphs/block)
        int sp = 32;
        int ga = sbatch[0];
        for (int i = 1; i < 32; ++i)
            if (sbatch[i] != ga) { sp = i; break; }
        ssplit = sp;
    }
    __syncthreads();

    // ---- phase 2: dense 32->64 x2 (bias + relu), 16 outputs/thread, static regs ----
    int ln2 = threadIdx.x >> 3;
    int q   = threadIdx.x & 7;            // chunk: global dims [q*16, q*16+16)
    int Dbase = q * 16;
    int koff = (q >= 4) ? 32 : 0;         // log branch reads agg dims 32..63
    float4 c0 = *(const float4*)&sbias[Dbase];
    float4 c1 = *(const float4*)&sbias[Dbase + 4];
    float4 c2 = *(const float4*)&sbias[Dbase + 8];
    float4 c3 = *(const float4*)&sbias[Dbase + 12];
    const float* ag = &agg[ln2 * 68 + koff];
    const float* wq = &sWall[q * 20];
    #pragma unroll
    for (int k = 0; k < 32; ++k) {
        float r = ag[k];
        const float* wr = &wq[k * 160];
        float4 w0 = *(const float4*)&wr[0];
        float4 w1 = *(const float4*)&wr[4];
        float4 w2 = *(const float4*)&wr[8];
        float4 w3 = *(const float4*)&wr[12];
        FMA4(c0, w0)
        FMA4(c1, w1)
        FMA4(c2, w2)
        FMA4(c3, w3)
    }
    c0.x = fmaxf(c0.x, 0.f); c0.y = fmaxf(c0.y, 0.f);
    c0.z = fmaxf(c0.z, 0.f); c0.w = fmaxf(c0.w, 0.f);
    c1.x = fmaxf(c1.x, 0.f); c1.y = fmaxf(c1.y, 0.f);
    c1.z = fmaxf(c1.z, 0.f); c1.w = fmaxf(c1.w, 0.f);
    c2.x = fmaxf(c2.x, 0.f); c2.y = fmaxf(c2.y, 0.f);
    c2.z = fmaxf(c2.z, 0.f); c2.w = fmaxf(c2.w, 0.f);
    c3.x = fmaxf(c3.x, 0.f); c3.y = fmaxf(c3.y, 0.f);
    c3.z = fmaxf(c3.z, 0.f); c3.w = fmaxf(c3.w, 0.f);
    __syncthreads();   // sWall dead; h3s may now overwrite it

    // ---- phase 3: stage h3 (linear [32][132], static writes), write partials ----
    {
        float* hp = &h3s[ln2 * 132 + Dbase];
        *(float4*)&hp[0]  = c0;
        *(float4*)&hp[4]  = c1;
        *(float4*)&hp[8]  = c2;
        *(float4*)&hp[12] = c3;
    }
    __syncthreads();
    {
        int d    = threadIdx.x & 127;
        int slot = threadIdx.x >> 7;      // 0: nodes [0,split)  1: [split,32)
        int sp = ssplit;
        int s = slot ? sp : 0;
        int e = slot ? 32 : sp;
        float acc = 0.f;
        for (int nn = s; nn < e; ++nn)
            acc += h3s[nn * 132 + d];
        if (slot == 0) {
            part0[(size_t)blk * 128 + d] = acc;
            if (d == 0) pg0[blk] = sbatch[0];
        } else {
            part1[(size_t)blk * 128 + d] = acc;
            if (d == 0) pg1[blk] = (sp < 32) ? sbatch[31] : -1;
        }
    }
}

// ---- pool reduce + reparameterize fused: block g sums tagged partials into
// LDS, then computes mu/logvar/z for its graph. No global pool buffer. ----
__global__ void __launch_bounds__(128) k_poolF(
        const float* __restrict__ part0, const float* __restrict__ part1,
        const int* __restrict__ pg0, const int* __restrict__ pg1,
        const int* __restrict__ batch, const float* __restrict__ eps,
        float* __restrict__ zbuf, float* __restrict__ out_mu,
        float* __restrict__ out_lv) {
    int g = blockIdx.x;
    __shared__ int sb[2];
    __shared__ float spool[128];
    if (threadIdx.x < 2) {
        int target = g + threadIdx.x;
        int lo = 0, hi = N_NODES;
        while (lo < hi) {
            int mid = (lo + hi) >> 1;
            if (batch[mid] < target) lo = mid + 1; else hi = mid;
        }
        sb[threadIdx.x] = lo;
    }
    __syncthreads();
    int ns = sb[0], ne = sb[1];
    int d = threadIdx.x;
    float acc = 0.f;
    if (ne > ns) {
        int b0 = ns >> 5, b1 = (ne - 1) >> 5;
        for (int b = b0; b <= b1; ++b) {
            if (pg0[b] == g) acc += part0[(size_t)b * 128 + d];
            if (pg1[b] == g) acc += part1[(size_t)b * 128 + d];
        }
    }
    spool[d] = acc;
    __syncthreads();
    if (threadIdx.x < 64) {
        int k = threadIdx.x;
        float c = fmaxf((float)(ne - ns), 1.0f);
        float mu = spool[k] / c;
        float lv = spool[64 + k] / c;
        zbuf[k * 64 + g] = mu + eps[g * 64 + k] * __expf(0.5f * lv);  // zT[k][g]
        out_mu[g * 64 + k] = mu;
        out_lv[g * 64 + k] = lv;
    }
}

// ------- dense: two-branch matmul, 4 outputs/thread; optional dinv out-scale -------
template<int IN_W, int OUT_HALF, int A_OFF, int A_W, int B_OFF, bool BR, bool OB, bool DS>
__global__ void k_dense4(const float* __restrict__ in,
                         const float* __restrict__ Wa, const float* __restrict__ ba,
                         const float* __restrict__ Wb, const float* __restrict__ bb,
                         const float* __restrict__ dinv,
                         void* __restrict__ out) {
    __shared__ float sWa[A_W * OUT_HALF];
    __shared__ float sWb[A_W * OUT_HALF];
    __shared__ float sba[OUT_HALF];
    __shared__ float sbb[OUT_HALF];
    for (int t = threadIdx.x; t < A_W * OUT_HALF; t += 256) {
        sWa[t] = Wa[t];
        sWb[t] = Wb[t];
    }
    if (BR && threadIdx.x < OUT_HALF) {
        sba[threadIdx.x] = ba[threadIdx.x];
        sbb[threadIdx.x] = bb[threadIdx.x];
    }
    __syncthreads();
    constexpr int TPN = OUT_HALF / 2;            // threads per node
    int idx = blockIdx.x * 256 + threadIdx.x;    // exact grid: N*TPN
    int n = idx / TPN;
    int q = idx % TPN;
    bool isB = (q * 4) >= OUT_HALF;
    int dd = q * 4 - (isB ? OUT_HALF : 0);
    const float* sW = isB ? sWb : sWa;
    int ko = isB ? B_OFF : A_OFF;
    float4 acc;
    if (BR) {
        const float* bp = isB ? (sbb + dd) : (sba + dd);
        acc = make_float4(bp[0], bp[1], bp[2], bp[3]);
    } else {
        acc = make_float4(0.f, 0.f, 0.f, 0.f);
    }
    const float* row = in + (size_t)n * IN_W + ko;
    #pragma unroll
    for (int k = 0; k < A_W; ++k) {
        float r = row[k];
        float4 wv = *(const float4*)&sW[k * OUT_HALF + dd];
        acc.x = fmaf(r, wv.x, acc.x);
        acc.y = fmaf(r, wv.y, acc.y);
        acc.z = fmaf(r, wv.z, acc.z);
        acc.w = fmaf(r, wv.w, acc.w);
    }
    if (BR) {
        acc.x = fmaxf(acc.x, 0.f); acc.y = fmaxf(acc.y, 0.f);
        acc.z = fmaxf(acc.z, 0.f); acc.w = fmaxf(acc.w, 0.f);
    }
    if (DS) {
        float dn = dinv[n];
        acc.x *= dn; acc.y *= dn; acc.z *= dn; acc.w *= dn;
    }
    if (OB) {
        ((uint2*)out)[idx] = make_uint2(pack2(acc.x, acc.y), pack2(acc.z, acc.w));
    } else {
        ((float4*)out)[idx] = acc;
    }
}

// ---------------- decode: sigmoid(z @ Wfc + bfc) ----------------
// zT is [64 k][64 g] k-major; all z accesses are wave-uniform -> s_load,
// FMAs become v_fmac_f32 vacc, s_z, v_w. No LDS. 32 accumulators/thread.
__global__ void __launch_bounds__(256) k_decode(const float* __restrict__ zT,
                                                const float* __restrict__ Wfc,
                                                const float* __restrict__ bfc,
                                                float* __restrict__ out) {
    int j = (blockIdx.x >> 1) * 256 + threadIdx.x;
    int gh = (blockIdx.x & 1) * 32;            // graph-half base
    const float* zp = zT + gh;                 // uniform pointer
    float bias = bfc[j];
    float acc[32];
    #pragma unroll
    for (int g = 0; g < 32; ++g) acc[g] = bias;
    #pragma unroll 8
    for (int k = 0; k < 64; ++k) {
        float w = Wfc[(size_t)k * 160000 + j];
        #pragma unroll
        for (int g = 0; g < 32; ++g)
            acc[g] = fmaf(zp[k * 64 + g], w, acc[g]);
    }
    #pragma unroll
    for (int g = 0; g < 32; ++g) {
        float s = 1.0f / (1.0f + __expf(-acc[g]));
        out[(size_t)(gh + g) * 160000 + j] = s;
    }
}

extern "C" void kernel_launch(void* const* d_in, const int* in_sizes, int n_in,
                              void* d_out, int out_size, void* d_ws, size_t ws_size,
                              hipStream_t stream) {
    const float* x     = (const float*)d_in[0];
    const int*   ei    = (const int*)d_in[1];
    const int*   batch = (const int*)d_in[2];
    const float *W1m = (const float*)d_in[3],  *b1m = (const float*)d_in[4];
    const float *W2m = (const float*)d_in[5],  *b2m = (const float*)d_in[6];
    const float *W3m = (const float*)d_in[7],  *b3m = (const float*)d_in[8];
    const float *W1l = (const float*)d_in[9],  *b1l = (const float*)d_in[10];
    const float *W2l = (const float*)d_in[11], *b2l = (const float*)d_in[12];
    const float *W3l = (const float*)d_in[13], *b3l = (const float*)d_in[14];
    const float *Wfc = (const float*)d_in[15], *bfc = (const float*)d_in[16];
    const float *eps = (const float*)d_in[17];

    const int* srcv = ei;
    const int* dstv = ei + N_EDGES;

    char* w = (char*)d_ws;
    auto alloc = [&](size_t bytes) -> char* {
        char* p = w;
        w += (bytes + 255) & ~(size_t)255;
        return p;
    };
    int*   gcount = (int*)  alloc((size_t)NB * 4);
    int*   gbase  = (int*)  alloc((size_t)NB * 4);
    int*   gcursor= (int*)  alloc((size_t)NB * 4);
    int*   rowptr = (int*)  alloc((size_t)(N_NODES + 1) * 4);
    float* dinv   = (float*)alloc((size_t)N_NODES * 4);
    float* zbuf   = (float*)alloc((size_t)N_GRAPHS * 64 * 4);
    // Arena (76.8 MB): A (N*64 f32) | B (N*64 f32) | csr (N_EDGES int) | spare
    //   A: dinv*xW bf16 -> A*h1 f32 -> A*h2 f32 (25.6 MB max); dead at k_gd3 time
    //   B: dinv*h1 bf16 -> dinv*h2 bf16 (12.8 MB max)
    //   partials (3.2 MB) alias A during k_gd3/k_poolF.
    float* arena = (float*)alloc((size_t)N_NODES * 192 * 4);
    float* A   = arena;
    float* B   = arena + (size_t)N_NODES * 64;
    int*   csr = (int*)(arena + (size_t)N_NODES * 128);
    float* part0 = A;                               // [NBLK3][128]
    float* part1 = A + (size_t)NBLK3 * 128;         // [NBLK3][128]
    int*   pg0   = (int*)(A + (size_t)2 * NBLK3 * 128);
    int*   pg1   = pg0 + NBLK3;

    float* out    = (float*)d_out;
    float* out_mu = out + 10240000;
    float* out_lv = out + 10240000 + 4096;

    hipMemsetAsync(gcount, 0, (size_t)NB * 4, stream);

    // ---- CSR build (binned) ----
    k_binCount<<<NCHUNK, 512, 0, stream>>>(dstv, gcount);
    k_scanB<<<1, 512, 0, stream>>>(gcount, gbase, gcursor, rowptr);
    k_binA<<<NCHUNK, 512, 0, stream>>>(srcv, dstv, gcursor, csr);
    k_passB<<<NB, 512, 0, stream>>>(gbase, csr, rowptr, dinv);

    // ---- L1: dense -> dinv*xW bf16; gather w32 -> dinv*relu(...) bf16 ----
    k_dense4<64, 16, 0, 64, 0, false, true, true><<<N_NODES * 8 / 256, 256, 0, stream>>>(
        x, W1m, b1m, W1l, b1l, dinv, A);
    k_gatherB<5, true, true, true><<<(N_NODES + 63) / 64, 256, 0, stream>>>(
        rowptr, csr, (const unsigned*)A, dinv, b1m, b1l, B);

    // ---- L2: gather w32 -> f32 agg; dense 16->32 x2 -> dinv*relu bf16 ----
    k_gatherB<5, false, false, false><<<(N_NODES + 63) / 64, 256, 0, stream>>>(
        rowptr, csr, (const unsigned*)B, dinv, b1m, b1l, A);
    k_dense4<32, 32, 0, 16, 16, true, true, true><<<N_NODES * 16 / 256, 256, 0, stream>>>(
        A, W2m, b2m, W2l, b2l, dinv, B);

    // ---- L3 fused: gather w64 + dense 32->64 x2 + pool partials ----
    // Two half-grid dispatches (profiler tier visibility; independent block ranges).
    k_gd3<<<NBLK3 / 2, 256, 0, stream>>>(
        rowptr, csr, (const unsigned*)B, dinv, W3m, b3m, W3l, b3l, batch,
        part0, part1, pg0, pg1, 0);
    k_gd3<<<NBLK3 - NBLK3 / 2, 256, 0, stream>>>(
        rowptr, csr, (const unsigned*)B, dinv, W3m, b3m, W3l, b3l, batch,
        part0, part1, pg0, pg1, NBLK3 / 2);

    // ---- pool reduce + reparameterize (fused) ----
    k_poolF<<<N_GRAPHS, 128, 0, stream>>>(part0, part1, pg0, pg1, batch, eps,
                                          zbuf, out_mu, out_lv);

    // ---- decode ----
    k_decode<<<1250, 256, 0, stream>>>(zbuf, Wfc, bfc, out);
}

// Round 7
// 434.585 us; speedup vs baseline: 1.0667x; 1.0667x over previous
//
#include <hip/hip_runtime.h>
#include <hip/hip_bf16.h>

#define N_NODES 100000
#define N_EDGES 3200000
#define N_GRAPHS 64
#define NB 391                 // dst-buckets of 256 nodes (last has 160)
#define KCH 8192               // edges per binning block
#define NCHUNK ((N_EDGES + KCH - 1) / KCH)   // 391
#define MAXBKT 10240           // passB staging capacity (mean 8192, sigma ~90)
#define NBLK3 (N_NODES / 32)   // 3125 fused-L3 blocks

__device__ __forceinline__ void atomAddF(float* p, float v) {
    unsafeAtomicAdd(p, v);
}

// bf16x2 pack/unpack (RTNE via __float2bfloat16)
__device__ __forceinline__ float lo2f(unsigned u) { return __uint_as_float(u << 16); }
__device__ __forceinline__ float hi2f(unsigned u) { return __uint_as_float(u & 0xFFFF0000u); }
__device__ __forceinline__ unsigned pack2(float a, float b) {
    unsigned ha = __bfloat16_as_ushort(__float2bfloat16(a));
    unsigned hb = __bfloat16_as_ushort(__float2bfloat16(b));
    return ha | (hb << 16);
}

// ---------------- CSR build: two-level binning ----------------
__global__ __launch_bounds__(512) void k_binCount(const int* __restrict__ dst,
                                                  int* __restrict__ gcount) {
    __shared__ int hist[NB];
    for (int t = threadIdx.x; t < NB; t += 512) hist[t] = 0;
    __syncthreads();
    int base = blockIdx.x * KCH;
    int cnt = min(KCH, N_EDGES - base);
    for (int i = threadIdx.x; i < cnt; i += 512)
        atomicAdd(&hist[dst[base + i] >> 8], 1);
    __syncthreads();
    for (int t = threadIdx.x; t < NB; t += 512)
        if (hist[t]) atomicAdd(&gcount[t], hist[t]);
}

__global__ __launch_bounds__(512) void k_scanB(const int* __restrict__ gcount,
                                               int* __restrict__ gbase,
                                               int* __restrict__ gcursor,
                                               int* __restrict__ rowptr) {
    __shared__ int s[512];
    int v = (threadIdx.x < NB) ? gcount[threadIdx.x] : 0;
    s[threadIdx.x] = v;
    __syncthreads();
    for (int off = 1; off < 512; off <<= 1) {
        int t = (threadIdx.x >= off) ? s[threadIdx.x - off] : 0;
        __syncthreads();
        s[threadIdx.x] += t;
        __syncthreads();
    }
    if (threadIdx.x < NB) {
        int e = s[threadIdx.x] - v;
        gbase[threadIdx.x] = e;
        gcursor[threadIdx.x] = e;
    }
    if (threadIdx.x == 0) rowptr[N_NODES] = N_EDGES;
}

// binA v2: STATIC per-thread arrays (rule #20), no LDS staging/scan/search.
// Per-bucket block reservation + direct dword scatter (L2 absorbs).
__global__ __launch_bounds__(512) void k_binA(const int* __restrict__ src,
                                              const int* __restrict__ dst,
                                              int* __restrict__ gcursor,
                                              int* __restrict__ binned) {
    __shared__ int hist[512];
    __shared__ int rbase[512];
    hist[threadIdx.x] = 0;
    __syncthreads();
    int base = blockIdx.x * KCH;
    int cnt = min(KCH, N_EDGES - base);
    int pk[16];    // packed (dst&255)<<24 | src
    int meta[16];  // (b<<13) | pos, or -1
    #pragma unroll
    for (int i = 0; i < 16; ++i) {
        int idx = i * 512 + threadIdx.x;
        if (idx < cnt) {
            int d = dst[base + idx];
            int b = d >> 8;
            int pos = atomicAdd(&hist[b], 1);        // pos < 8192 -> 13 bits
            pk[i] = ((d & 255) << 24) | src[base + idx];
            meta[i] = (b << 13) | pos;
        } else {
            meta[i] = -1;
        }
    }
    __syncthreads();
    if (threadIdx.x < NB) {
        int v = hist[threadIdx.x];
        if (v > 0) rbase[threadIdx.x] = atomicAdd(&gcursor[threadIdx.x], v);
    }
    __syncthreads();
    #pragma unroll
    for (int i = 0; i < 16; ++i) {
        if (meta[i] >= 0) {
            int b = meta[i] >> 13;
            int pos = meta[i] & 8191;
            binned[rbase[b] + pos] = pk[i];
        }
    }
}

__global__ __launch_bounds__(512) void k_passB(const int* __restrict__ gbase,
                                               int* __restrict__ csr,
                                               int* __restrict__ rowptr,
                                               float* __restrict__ dinv) {
    int b = blockIdx.x;
    int rb = gbase[b];
    int re = (b == NB - 1) ? N_EDGES : gbase[b + 1];
    int cnt = re - rb;
    int nbase = b << 8;
    int nn = min(nbase + 256, N_NODES) - nbase;
    __shared__ int stage[MAXBKT];   // 40 KB
    __shared__ int nhist[256];
    __shared__ int sc[256];
    __shared__ int ncur[256];
    for (int t = threadIdx.x; t < 256; t += 512) nhist[t] = 0;
    __syncthreads();
    for (int j = threadIdx.x; j < cnt; j += 512) {
        int p = csr[rb + j];
        stage[j] = p;
        atomicAdd(&nhist[((unsigned)p) >> 24], 1);
    }
    __syncthreads();
    if (threadIdx.x < 256) sc[threadIdx.x] = nhist[threadIdx.x];
    __syncthreads();
    for (int off = 1; off < 256; off <<= 1) {
        int t = (threadIdx.x < 256 && threadIdx.x >= off) ? sc[threadIdx.x - off] : 0;
        __syncthreads();
        if (threadIdx.x < 256) sc[threadIdx.x] += t;
        __syncthreads();
    }
    if (threadIdx.x < 256) {
        int e = sc[threadIdx.x] - nhist[threadIdx.x];
        ncur[threadIdx.x] = e;
        if (threadIdx.x < nn) {
            rowptr[nbase + threadIdx.x] = rb + e;
            dinv[nbase + threadIdx.x] = rsqrtf((float)nhist[threadIdx.x] + 1.0f);
        }
    }
    __syncthreads();
    for (int j = threadIdx.x; j < cnt; j += 512) {
        int p = stage[j];
        int slot = atomicAdd(&ncur[((unsigned)p) >> 24], 1);
        csr[rb + slot] = p;
    }
}

// -------- gather: out = di*(sum A'[s] + A'[n]) (+bias,relu) --------
template<int LOGW, bool BIAS_RELU, bool OB, bool PRE>
__global__ void __launch_bounds__(256) k_gatherB(
        const int* __restrict__ rowptr, const int* __restrict__ csr,
        const unsigned* __restrict__ in /* bf16x2 pairs, prescaled */,
        const float* __restrict__ dinv,
        const float* __restrict__ ba, const float* __restrict__ bb,
        void* __restrict__ out) {
    constexpr int W8 = (1 << LOGW) / 8;   // lanes per node (uint4 = 8 bf16)
    constexpr int NPB = 256 / W8;         // nodes per block
    int n = blockIdx.x * NPB + (threadIdx.x / W8);
    if (n >= N_NODES) return;
    int sub = threadIdx.x % W8;
    const uint4* in4 = (const uint4*)in;
    uint4 u = in4[(size_t)n * W8 + sub];              // self term A'[n]
    float a0 = lo2f(u.x), a1 = hi2f(u.x), a2 = lo2f(u.y), a3 = hi2f(u.y);
    float a4 = lo2f(u.z), a5 = hi2f(u.z), a6 = lo2f(u.w), a7 = hi2f(u.w);
    int j = rowptr[n], end = rowptr[n + 1];
    for (; j + 8 <= end; j += 8) {
        int s0 = csr[j] & 0xFFFFFF;
        int s1 = csr[j + 1] & 0xFFFFFF;
        int s2 = csr[j + 2] & 0xFFFFFF;
        int s3 = csr[j + 3] & 0xFFFFFF;
        int s4 = csr[j + 4] & 0xFFFFFF;
        int s5 = csr[j + 5] & 0xFFFFFF;
        int s6 = csr[j + 6] & 0xFFFFFF;
        int s7 = csr[j + 7] & 0xFFFFFF;
        uint4 v0 = in4[(size_t)s0 * W8 + sub];
        uint4 v1 = in4[(size_t)s1 * W8 + sub];
        uint4 v2 = in4[(size_t)s2 * W8 + sub];
        uint4 v3 = in4[(size_t)s3 * W8 + sub];
        uint4 v4 = in4[(size_t)s4 * W8 + sub];
        uint4 v5 = in4[(size_t)s5 * W8 + sub];
        uint4 v6 = in4[(size_t)s6 * W8 + sub];
        uint4 v7 = in4[(size_t)s7 * W8 + sub];
        a0 += ((lo2f(v0.x) + lo2f(v1.x)) + (lo2f(v2.x) + lo2f(v3.x)))
            + ((lo2f(v4.x) + lo2f(v5.x)) + (lo2f(v6.x) + lo2f(v7.x)));
        a1 += ((hi2f(v0.x) + hi2f(v1.x)) + (hi2f(v2.x) + hi2f(v3.x)))
            + ((hi2f(v4.x) + hi2f(v5.x)) + (hi2f(v6.x) + hi2f(v7.x)));
        a2 += ((lo2f(v0.y) + lo2f(v1.y)) + (lo2f(v2.y) + lo2f(v3.y)))
            + ((lo2f(v4.y) + lo2f(v5.y)) + (lo2f(v6.y) + lo2f(v7.y)));
        a3 += ((hi2f(v0.y) + hi2f(v1.y)) + (hi2f(v2.y) + hi2f(v3.y)))
            + ((hi2f(v4.y) + hi2f(v5.y)) + (hi2f(v6.y) + hi2f(v7.y)));
        a4 += ((lo2f(v0.z) + lo2f(v1.z)) + (lo2f(v2.z) + lo2f(v3.z)))
            + ((lo2f(v4.z) + lo2f(v5.z)) + (lo2f(v6.z) + lo2f(v7.z)));
        a5 += ((hi2f(v0.z) + hi2f(v1.z)) + (hi2f(v2.z) + hi2f(v3.z)))
            + ((hi2f(v4.z) + hi2f(v5.z)) + (hi2f(v6.z) + hi2f(v7.z)));
        a6 += ((lo2f(v0.w) + lo2f(v1.w)) + (lo2f(v2.w) + lo2f(v3.w)))
            + ((lo2f(v4.w) + lo2f(v5.w)) + (lo2f(v6.w) + lo2f(v7.w)));
        a7 += ((hi2f(v0.w) + hi2f(v1.w)) + (hi2f(v2.w) + hi2f(v3.w)))
            + ((hi2f(v4.w) + hi2f(v5.w)) + (hi2f(v6.w) + hi2f(v7.w)));
    }
    for (; j < end; ++j) {
        int s = csr[j] & 0xFFFFFF;
        uint4 v = in4[(size_t)s * W8 + sub];
        a0 += lo2f(v.x); a1 += hi2f(v.x);
        a2 += lo2f(v.y); a3 += hi2f(v.y);
        a4 += lo2f(v.z); a5 += hi2f(v.z);
        a6 += lo2f(v.w); a7 += hi2f(v.w);
    }
    float di = dinv[n];
    a0 *= di; a1 *= di; a2 *= di; a3 *= di;
    a4 *= di; a5 *= di; a6 *= di; a7 *= di;
    if (BIAS_RELU) {
        constexpr int H = (1 << LOGW) / 2;
        int d = sub * 8;                 // 8 | H for all instantiations
        const float* bp = (d < H) ? (ba + d) : (bb + d - H);
        a0 = fmaxf(a0 + bp[0], 0.0f);
        a1 = fmaxf(a1 + bp[1], 0.0f);
        a2 = fmaxf(a2 + bp[2], 0.0f);
        a3 = fmaxf(a3 + bp[3], 0.0f);
        a4 = fmaxf(a4 + bp[4], 0.0f);
        a5 = fmaxf(a5 + bp[5], 0.0f);
        a6 = fmaxf(a6 + bp[6], 0.0f);
        a7 = fmaxf(a7 + bp[7], 0.0f);
    }
    if (PRE) {  // pre-scale for the NEXT gather layer
        a0 *= di; a1 *= di; a2 *= di; a3 *= di;
        a4 *= di; a5 *= di; a6 *= di; a7 *= di;
    }
    if (OB) {
        ((uint4*)out)[(size_t)n * W8 + sub] =
            make_uint4(pack2(a0, a1), pack2(a2, a3), pack2(a4, a5), pack2(a6, a7));
    } else {
        constexpr int OUT4 = (1 << LOGW) / 4;
        float4* o4 = (float4*)out;
        o4[(size_t)n * OUT4 + sub * 2]     = make_float4(a0, a1, a2, a3);
        o4[(size_t)n * OUT4 + sub * 2 + 1] = make_float4(a4, a5, a6, a7);
    }
}

#define FMA4(A, W) \
    A.x = fmaf(r, W.x, A.x); A.y = fmaf(r, W.y, A.y); \
    A.z = fmaf(r, W.z, A.z); A.w = fmaf(r, W.w, A.w);

// ======== fused L2: gather(w32) + dense(16->32 x2, bias+relu) + prescaled bf16 out ========
// Block = 256 threads = 64 nodes x 4 lanes. gd3 template lessons applied:
// static regs only; weight chunks padded 16->20 (banks 20q mod 32 distinct);
// agg row stride 37 (5*ln mod 32 is a permutation; koff=16 in disjoint residues
// -> dense reads conflict-free; gather writes 2-way = free).
__global__ void __launch_bounds__(256) k_gd2(
        const int* __restrict__ rowptr, const int* __restrict__ csr,
        const unsigned* __restrict__ in,     // B: bf16x2 h1, dinv-prescaled, 32 dims
        const float* __restrict__ dinv,
        const float* __restrict__ W2m, const float* __restrict__ b2m,
        const float* __restrict__ W2l, const float* __restrict__ b2l,
        unsigned* __restrict__ outB) {       // B2: 64 bf16 dims/node, prescaled
    __shared__ float sW[16 * 80];    // 5 KB: [16 k][chunk q: q*20 + 0..15]
    __shared__ float agg[64 * 37];   // 9.5 KB
    __shared__ float sbias[64];
    for (int t = threadIdx.x; t < 1024; t += 256) {
        int k = t >> 6, D = t & 63;
        float wv = (D < 32) ? W2m[k * 32 + D] : W2l[k * 32 + (D - 32)];
        sW[k * 80 + (D >> 4) * 20 + (D & 15)] = wv;
    }
    if (threadIdx.x < 64)
        sbias[threadIdx.x] = (threadIdx.x < 32) ? b2m[threadIdx.x]
                                                : b2l[threadIdx.x - 32];
    int ln  = threadIdx.x >> 2;
    int sub = threadIdx.x & 3;
    int n = blockIdx.x * 64 + ln;
    int nc = min(n, N_NODES - 1);        // clamp; invalid nodes never stored
    const uint4* in4 = (const uint4*)in;
    uint4 u = in4[(size_t)nc * 4 + sub];
    float a0 = lo2f(u.x), a1 = hi2f(u.x), a2 = lo2f(u.y), a3 = hi2f(u.y);
    float a4 = lo2f(u.z), a5 = hi2f(u.z), a6 = lo2f(u.w), a7 = hi2f(u.w);
    int j = rowptr[nc], end = rowptr[nc + 1];
    for (; j + 8 <= end; j += 8) {
        int s0 = csr[j] & 0xFFFFFF;
        int s1 = csr[j + 1] & 0xFFFFFF;
        int s2 = csr[j + 2] & 0xFFFFFF;
        int s3 = csr[j + 3] & 0xFFFFFF;
        int s4 = csr[j + 4] & 0xFFFFFF;
        int s5 = csr[j + 5] & 0xFFFFFF;
        int s6 = csr[j + 6] & 0xFFFFFF;
        int s7 = csr[j + 7] & 0xFFFFFF;
        uint4 v0 = in4[(size_t)s0 * 4 + sub];
        uint4 v1 = in4[(size_t)s1 * 4 + sub];
        uint4 v2 = in4[(size_t)s2 * 4 + sub];
        uint4 v3 = in4[(size_t)s3 * 4 + sub];
        uint4 v4 = in4[(size_t)s4 * 4 + sub];
        uint4 v5 = in4[(size_t)s5 * 4 + sub];
        uint4 v6 = in4[(size_t)s6 * 4 + sub];
        uint4 v7 = in4[(size_t)s7 * 4 + sub];
        a0 += ((lo2f(v0.x) + lo2f(v1.x)) + (lo2f(v2.x) + lo2f(v3.x)))
            + ((lo2f(v4.x) + lo2f(v5.x)) + (lo2f(v6.x) + lo2f(v7.x)));
        a1 += ((hi2f(v0.x) + hi2f(v1.x)) + (hi2f(v2.x) + hi2f(v3.x)))
            + ((hi2f(v4.x) + hi2f(v5.x)) + (hi2f(v6.x) + hi2f(v7.x)));
        a2 += ((lo2f(v0.y) + lo2f(v1.y)) + (lo2f(v2.y) + lo2f(v3.y)))
            + ((lo2f(v4.y) + lo2f(v5.y)) + (lo2f(v6.y) + lo2f(v7.y)));
        a3 += ((hi2f(v0.y) + hi2f(v1.y)) + (hi2f(v2.y) + hi2f(v3.y)))
            + ((hi2f(v4.y) + hi2f(v5.y)) + (hi2f(v6.y) + hi2f(v7.y)));
        a4 += ((lo2f(v0.z) + lo2f(v1.z)) + (lo2f(v2.z) + lo2f(v3.z)))
            + ((lo2f(v4.z) + lo2f(v5.z)) + (lo2f(v6.z) + lo2f(v7.z)));
        a5 += ((hi2f(v0.z) + hi2f(v1.z)) + (hi2f(v2.z) + hi2f(v3.z)))
            + ((hi2f(v4.z) + hi2f(v5.z)) + (hi2f(v6.z) + hi2f(v7.z)));
        a6 += ((lo2f(v0.w) + lo2f(v1.w)) + (lo2f(v2.w) + lo2f(v3.w)))
            + ((lo2f(v4.w) + lo2f(v5.w)) + (lo2f(v6.w) + lo2f(v7.w)));
        a7 += ((hi2f(v0.w) + hi2f(v1.w)) + (hi2f(v2.w) + hi2f(v3.w)))
            + ((hi2f(v4.w) + hi2f(v5.w)) + (hi2f(v6.w) + hi2f(v7.w)));
    }
    for (; j < end; ++j) {
        int s = csr[j] & 0xFFFFFF;
        uint4 v = in4[(size_t)s * 4 + sub];
        a0 += lo2f(v.x); a1 += hi2f(v.x);
        a2 += lo2f(v.y); a3 += hi2f(v.y);
        a4 += lo2f(v.z); a5 += hi2f(v.z);
        a6 += lo2f(v.w); a7 += hi2f(v.w);
    }
    float di = dinv[nc];
    a0 *= di; a1 *= di; a2 *= di; a3 *= di;
    a4 *= di; a5 *= di; a6 *= di; a7 *= di;
    {
        float* ap = &agg[ln * 37 + sub * 8];
        *(float4*)&ap[0] = make_float4(a0, a1, a2, a3);
        *(float4*)&ap[4] = make_float4(a4, a5, a6, a7);
    }
    __syncthreads();

    // ---- dense 16->32 x2 (bias + relu + dinv prescale), 16 outputs/thread ----
    int q = sub;                          // chunk: global dims [q*16, q*16+16)
    int Dbase = q * 16;
    int koff = (q >= 2) ? 16 : 0;         // log branch reads agg dims 16..31
    float4 c0 = *(const float4*)&sbias[Dbase];
    float4 c1 = *(const float4*)&sbias[Dbase + 4];
    float4 c2 = *(const float4*)&sbias[Dbase + 8];
    float4 c3 = *(const float4*)&sbias[Dbase + 12];
    const float* ag = &agg[ln * 37 + koff];
    const float* wq = &sW[q * 20];
    #pragma unroll
    for (int k = 0; k < 16; ++k) {
        float r = ag[k];
        const float* wr = &wq[k * 80];
        float4 w0 = *(const float4*)&wr[0];
        float4 w1 = *(const float4*)&wr[4];
        float4 w2 = *(const float4*)&wr[8];
        float4 w3 = *(const float4*)&wr[12];
        FMA4(c0, w0)
        FMA4(c1, w1)
        FMA4(c2, w2)
        FMA4(c3, w3)
    }
    c0.x = fmaxf(c0.x, 0.f) * di; c0.y = fmaxf(c0.y, 0.f) * di;
    c0.z = fmaxf(c0.z, 0.f) * di; c0.w = fmaxf(c0.w, 0.f) * di;
    c1.x = fmaxf(c1.x, 0.f) * di; c1.y = fmaxf(c1.y, 0.f) * di;
    c1.z = fmaxf(c1.z, 0.f) * di; c1.w = fmaxf(c1.w, 0.f) * di;
    c2.x = fmaxf(c2.x, 0.f) * di; c2.y = fmaxf(c2.y, 0.f) * di;
    c2.z = fmaxf(c2.z, 0.f) * di; c2.w = fmaxf(c2.w, 0.f) * di;
    c3.x = fmaxf(c3.x, 0.f) * di; c3.y = fmaxf(c3.y, 0.f) * di;
    c3.z = fmaxf(c3.z, 0.f) * di; c3.w = fmaxf(c3.w, 0.f) * di;
    if (n < N_NODES) {
        uint4* o4 = (uint4*)outB;
        o4[(size_t)n * 8 + q * 2] =
            make_uint4(pack2(c0.x, c0.y), pack2(c0.z, c0.w),
                       pack2(c1.x, c1.y), pack2(c1.z, c1.w));
        o4[(size_t)n * 8 + q * 2 + 1] =
            make_uint4(pack2(c2.x, c2.y), pack2(c2.z, c2.w),
                       pack2(c3.x, c3.y), pack2(c3.z, c3.w));
    }
}

// ======== fused L3: gather(w64) + dense(32->64 x2, bias+relu) + pool-partials ========
// Block = 256 threads = 32 nodes x 8 lanes. Static regs; weight chunks padded
// 16->20; agg row stride 68. SINGLE dispatch (R5 split cost +21us).
__global__ void __launch_bounds__(256) k_gd3(
        const int* __restrict__ rowptr, const int* __restrict__ csr,
        const unsigned* __restrict__ in,     // B2: bf16x2, dinv-prescaled, 64 dims
        const float* __restrict__ dinv,
        const float* __restrict__ W3m, const float* __restrict__ b3m,
        const float* __restrict__ W3l, const float* __restrict__ b3l,
        const int* __restrict__ batch,
        float* __restrict__ part0, float* __restrict__ part1,
        int* __restrict__ pg0, int* __restrict__ pg1) {
    __shared__ float s_ali[32 * 160];     // 20.5 KB: sWall (p2) / h3s (p3)
    __shared__ float agg[32 * 68];        // 8.7 KB
    __shared__ float sbias[128];
    __shared__ int   sbatch[32];
    __shared__ int   ssplit;
    float* sWall = s_ali;                 // [32 k][chunk q: q*20 + 0..15]
    float* h3s   = s_ali;                 // [32 n][132]

    for (int t = threadIdx.x; t < 4096; t += 256) {
        int k = t >> 7, D = t & 127;
        float wv = (D < 64) ? W3m[k * 64 + D] : W3l[k * 64 + (D - 64)];
        sWall[k * 160 + (D >> 4) * 20 + (D & 15)] = wv;
    }
    if (threadIdx.x < 128)
        sbias[threadIdx.x] = (threadIdx.x < 64) ? b3m[threadIdx.x]
                                                : b3l[threadIdx.x - 64];
    int nbase = blockIdx.x * 32;
    if (threadIdx.x < 32) sbatch[threadIdx.x] = batch[nbase + threadIdx.x];

    // ---- phase 1: gather ----
    int ln  = threadIdx.x >> 3;
    int sub = threadIdx.x & 7;
    int n = nbase + ln;
    const uint4* in4 = (const uint4*)in;
    uint4 u = in4[(size_t)n * 8 + sub];
    float a0 = lo2f(u.x), a1 = hi2f(u.x), a2 = lo2f(u.y), a3 = hi2f(u.y);
    float a4 = lo2f(u.z), a5 = hi2f(u.z), a6 = lo2f(u.w), a7 = hi2f(u.w);
    int j = rowptr[n], end = rowptr[n + 1];
    for (; j + 8 <= end; j += 8) {
        int s0 = csr[j] & 0xFFFFFF;
        int s1 = csr[j + 1] & 0xFFFFFF;
        int s2 = csr[j + 2] & 0xFFFFFF;
        int s3 = csr[j + 3] & 0xFFFFFF;
        int s4 = csr[j + 4] & 0xFFFFFF;
        int s5 = csr[j + 5] & 0xFFFFFF;
        int s6 = csr[j + 6] & 0xFFFFFF;
        int s7 = csr[j + 7] & 0xFFFFFF;
        uint4 v0 = in4[(size_t)s0 * 8 + sub];
        uint4 v1 = in4[(size_t)s1 * 8 + sub];
        uint4 v2 = in4[(size_t)s2 * 8 + sub];
        uint4 v3 = in4[(size_t)s3 * 8 + sub];
        uint4 v4 = in4[(size_t)s4 * 8 + sub];
        uint4 v5 = in4[(size_t)s5 * 8 + sub];
        uint4 v6 = in4[(size_t)s6 * 8 + sub];
        uint4 v7 = in4[(size_t)s7 * 8 + sub];
        a0 += ((lo2f(v0.x) + lo2f(v1.x)) + (lo2f(v2.x) + lo2f(v3.x)))
            + ((lo2f(v4.x) + lo2f(v5.x)) + (lo2f(v6.x) + lo2f(v7.x)));
        a1 += ((hi2f(v0.x) + hi2f(v1.x)) + (hi2f(v2.x) + hi2f(v3.x)))
            + ((hi2f(v4.x) + hi2f(v5.x)) + (hi2f(v6.x) + hi2f(v7.x)));
        a2 += ((lo2f(v0.y) + lo2f(v1.y)) + (lo2f(v2.y) + lo2f(v3.y)))
            + ((lo2f(v4.y) + lo2f(v5.y)) + (lo2f(v6.y) + lo2f(v7.y)));
        a3 += ((hi2f(v0.y) + hi2f(v1.y)) + (hi2f(v2.y) + hi2f(v3.y)))
            + ((hi2f(v4.y) + hi2f(v5.y)) + (hi2f(v6.y) + hi2f(v7.y)));
        a4 += ((lo2f(v0.z) + lo2f(v1.z)) + (lo2f(v2.z) + lo2f(v3.z)))
            + ((lo2f(v4.z) + lo2f(v5.z)) + (lo2f(v6.z) + lo2f(v7.z)));
        a5 += ((hi2f(v0.z) + hi2f(v1.z)) + (hi2f(v2.z) + hi2f(v3.z)))
            + ((hi2f(v4.z) + hi2f(v5.z)) + (hi2f(v6.z) + hi2f(v7.z)));
        a6 += ((lo2f(v0.w) + lo2f(v1.w)) + (lo2f(v2.w) + lo2f(v3.w)))
            + ((lo2f(v4.w) + lo2f(v5.w)) + (lo2f(v6.w) + lo2f(v7.w)));
        a7 += ((hi2f(v0.w) + hi2f(v1.w)) + (hi2f(v2.w) + hi2f(v3.w)))
            + ((hi2f(v4.w) + hi2f(v5.w)) + (hi2f(v6.w) + hi2f(v7.w)));
    }
    for (; j < end; ++j) {
        int s = csr[j] & 0xFFFFFF;
        uint4 v = in4[(size_t)s * 8 + sub];
        a0 += lo2f(v.x); a1 += hi2f(v.x);
        a2 += lo2f(v.y); a3 += hi2f(v.y);
        a4 += lo2f(v.z); a5 += hi2f(v.z);
        a6 += lo2f(v.w); a7 += hi2f(v.w);
    }
    float di = dinv[n];
    a0 *= di; a1 *= di; a2 *= di; a3 *= di;
    a4 *= di; a5 *= di; a6 *= di; a7 *= di;
    {
        float* ap = &agg[ln * 68 + sub * 8];
        *(float4*)&ap[0] = make_float4(a0, a1, a2, a3);
        *(float4*)&ap[4] = make_float4(a4, a5, a6, a7);
    }
    if (threadIdx.x == 0) {               // segment split (<=2 graphs/block)
        int sp = 32;
        int ga = sbatch[0];
        for (int i = 1; i < 32; ++i)
            if (sbatch[i] != ga) { sp = i; break; }
        ssplit = sp;
    }
    __syncthreads();

    // ---- phase 2: dense 32->64 x2 (bias + relu), 16 outputs/thread, static regs ----
    int ln2 = threadIdx.x >> 3;
    int q   = threadIdx.x & 7;            // chunk: global dims [q*16, q*16+16)
    int Dbase = q * 16;
    int koff = (q >= 4) ? 32 : 0;         // log branch reads agg dims 32..63
    float4 c0 = *(const float4*)&sbias[Dbase];
    float4 c1 = *(const float4*)&sbias[Dbase + 4];
    float4 c2 = *(const float4*)&sbias[Dbase + 8];
    float4 c3 = *(const float4*)&sbias[Dbase + 12];
    const float* ag = &agg[ln2 * 68 + koff];
    const float* wq = &sWall[q * 20];
    #pragma unroll
    for (int k = 0; k < 32; ++k) {
        float r = ag[k];
        const float* wr = &wq[k * 160];
        float4 w0 = *(const float4*)&wr[0];
        float4 w1 = *(const float4*)&wr[4];
        float4 w2 = *(const float4*)&wr[8];
        float4 w3 = *(const float4*)&wr[12];
        FMA4(c0, w0)
        FMA4(c1, w1)
        FMA4(c2, w2)
        FMA4(c3, w3)
    }
    c0.x = fmaxf(c0.x, 0.f); c0.y = fmaxf(c0.y, 0.f);
    c0.z = fmaxf(c0.z, 0.f); c0.w = fmaxf(c0.w, 0.f);
    c1.x = fmaxf(c1.x, 0.f); c1.y = fmaxf(c1.y, 0.f);
    c1.z = fmaxf(c1.z, 0.f); c1.w = fmaxf(c1.w, 0.f);
    c2.x = fmaxf(c2.x, 0.f); c2.y = fmaxf(c2.y, 0.f);
    c2.z = fmaxf(c2.z, 0.f); c2.w = fmaxf(c2.w, 0.f);
    c3.x = fmaxf(c3.x, 0.f); c3.y = fmaxf(c3.y, 0.f);
    c3.z = fmaxf(c3.z, 0.f); c3.w = fmaxf(c3.w, 0.f);
    __syncthreads();   // sWall dead; h3s may now overwrite it

    // ---- phase 3: stage h3 (linear [32][132], static writes), write partials ----
    {
        float* hp = &h3s[ln2 * 132 + Dbase];
        *(float4*)&hp[0]  = c0;
        *(float4*)&hp[4]  = c1;
        *(float4*)&hp[8]  = c2;
        *(float4*)&hp[12] = c3;
    }
    __syncthreads();
    {
        int d    = threadIdx.x & 127;
        int slot = threadIdx.x >> 7;      // 0: nodes [0,split)  1: [split,32)
        int sp = ssplit;
        int s = slot ? sp : 0;
        int e = slot ? 32 : sp;
        float acc = 0.f;
        for (int nn = s; nn < e; ++nn)
            acc += h3s[nn * 132 + d];
        int blk = blockIdx.x;
        if (slot == 0) {
            part0[(size_t)blk * 128 + d] = acc;
            if (d == 0) pg0[blk] = sbatch[0];
        } else {
            part1[(size_t)blk * 128 + d] = acc;
            if (d == 0) pg1[blk] = (sp < 32) ? sbatch[31] : -1;
        }
    }
}

// ---- pool reduce + reparameterize fused ----
__global__ void __launch_bounds__(128) k_poolF(
        const float* __restrict__ part0, const float* __restrict__ part1,
        const int* __restrict__ pg0, const int* __restrict__ pg1,
        const int* __restrict__ batch, const float* __restrict__ eps,
        float* __restrict__ zbuf, float* __restrict__ out_mu,
        float* __restrict__ out_lv) {
    int g = blockIdx.x;
    __shared__ int sb[2];
    __shared__ float spool[128];
    if (threadIdx.x < 2) {
        int target = g + threadIdx.x;
        int lo = 0, hi = N_NODES;
        while (lo < hi) {
            int mid = (lo + hi) >> 1;
            if (batch[mid] < target) lo = mid + 1; else hi = mid;
        }
        sb[threadIdx.x] = lo;
    }
    __syncthreads();
    int ns = sb[0], ne = sb[1];
    int d = threadIdx.x;
    float acc = 0.f;
    if (ne > ns) {
        int b0 = ns >> 5, b1 = (ne - 1) >> 5;
        for (int b = b0; b <= b1; ++b) {
            if (pg0[b] == g) acc += part0[(size_t)b * 128 + d];
            if (pg1[b] == g) acc += part1[(size_t)b * 128 + d];
        }
    }
    spool[d] = acc;
    __syncthreads();
    if (threadIdx.x < 64) {
        int k = threadIdx.x;
        float c = fmaxf((float)(ne - ns), 1.0f);
        float mu = spool[k] / c;
        float lv = spool[64 + k] / c;
        zbuf[k * 64 + g] = mu + eps[g * 64 + k] * __expf(0.5f * lv);  // zT[k][g]
        out_mu[g * 64 + k] = mu;
        out_lv[g * 64 + k] = lv;
    }
}

// ------- dense: two-branch matmul, 4 outputs/thread; optional dinv out-scale -------
template<int IN_W, int OUT_HALF, int A_OFF, int A_W, int B_OFF, bool BR, bool OB, bool DS>
__global__ void k_dense4(const float* __restrict__ in,
                         const float* __restrict__ Wa, const float* __restrict__ ba,
                         const float* __restrict__ Wb, const float* __restrict__ bb,
                         const float* __restrict__ dinv,
                         void* __restrict__ out) {
    __shared__ float sWa[A_W * OUT_HALF];
    __shared__ float sWb[A_W * OUT_HALF];
    __shared__ float sba[OUT_HALF];
    __shared__ float sbb[OUT_HALF];
    for (int t = threadIdx.x; t < A_W * OUT_HALF; t += 256) {
        sWa[t] = Wa[t];
        sWb[t] = Wb[t];
    }
    if (BR && threadIdx.x < OUT_HALF) {
        sba[threadIdx.x] = ba[threadIdx.x];
        sbb[threadIdx.x] = bb[threadIdx.x];
    }
    __syncthreads();
    constexpr int TPN = OUT_HALF / 2;            // threads per node
    int idx = blockIdx.x * 256 + threadIdx.x;    // exact grid: N*TPN
    int n = idx / TPN;
    int q = idx % TPN;
    bool isB = (q * 4) >= OUT_HALF;
    int dd = q * 4 - (isB ? OUT_HALF : 0);
    const float* sW = isB ? sWb : sWa;
    int ko = isB ? B_OFF : A_OFF;
    float4 acc;
    if (BR) {
        const float* bp = isB ? (sbb + dd) : (sba + dd);
        acc = make_float4(bp[0], bp[1], bp[2], bp[3]);
    } else {
        acc = make_float4(0.f, 0.f, 0.f, 0.f);
    }
    const float* row = in + (size_t)n * IN_W + ko;
    #pragma unroll
    for (int k = 0; k < A_W; ++k) {
        float r = row[k];
        float4 wv = *(const float4*)&sW[k * OUT_HALF + dd];
        acc.x = fmaf(r, wv.x, acc.x);
        acc.y = fmaf(r, wv.y, acc.y);
        acc.z = fmaf(r, wv.z, acc.z);
        acc.w = fmaf(r, wv.w, acc.w);
    }
    if (BR) {
        acc.x = fmaxf(acc.x, 0.f); acc.y = fmaxf(acc.y, 0.f);
        acc.z = fmaxf(acc.z, 0.f); acc.w = fmaxf(acc.w, 0.f);
    }
    if (DS) {
        float dn = dinv[n];
        acc.x *= dn; acc.y *= dn; acc.z *= dn; acc.w *= dn;
    }
    if (OB) {
        ((uint2*)out)[idx] = make_uint2(pack2(acc.x, acc.y), pack2(acc.z, acc.w));
    } else {
        ((float4*)out)[idx] = acc;
    }
}

// ---------------- decode: sigmoid(z @ Wfc + bfc) ----------------
__global__ void __launch_bounds__(256) k_decode(const float* __restrict__ zT,
                                                const float* __restrict__ Wfc,
                                                const float* __restrict__ bfc,
                                                float* __restrict__ out) {
    int j = (blockIdx.x >> 1) * 256 + threadIdx.x;
    int gh = (blockIdx.x & 1) * 32;            // graph-half base
    const float* zp = zT + gh;                 // uniform pointer
    float bias = bfc[j];
    float acc[32];
    #pragma unroll
    for (int g = 0; g < 32; ++g) acc[g] = bias;
    #pragma unroll 8
    for (int k = 0; k < 64; ++k) {
        float w = Wfc[(size_t)k * 160000 + j];
        #pragma unroll
        for (int g = 0; g < 32; ++g)
            acc[g] = fmaf(zp[k * 64 + g], w, acc[g]);
    }
    #pragma unroll
    for (int g = 0; g < 32; ++g) {
        float s = 1.0f / (1.0f + __expf(-acc[g]));
        out[(size_t)(gh + g) * 160000 + j] = s;
    }
}

extern "C" void kernel_launch(void* const* d_in, const int* in_sizes, int n_in,
                              void* d_out, int out_size, void* d_ws, size_t ws_size,
                              hipStream_t stream) {
    const float* x     = (const float*)d_in[0];
    const int*   ei    = (const int*)d_in[1];
    const int*   batch = (const int*)d_in[2];
    const float *W1m = (const float*)d_in[3],  *b1m = (const float*)d_in[4];
    const float *W2m = (const float*)d_in[5],  *b2m = (const float*)d_in[6];
    const float *W3m = (const float*)d_in[7],  *b3m = (const float*)d_in[8];
    const float *W1l = (const float*)d_in[9],  *b1l = (const float*)d_in[10];
    const float *W2l = (const float*)d_in[11], *b2l = (const float*)d_in[12];
    const float *W3l = (const float*)d_in[13], *b3l = (const float*)d_in[14];
    const float *Wfc = (const float*)d_in[15], *bfc = (const float*)d_in[16];
    const float *eps = (const float*)d_in[17];

    const int* srcv = ei;
    const int* dstv = ei + N_EDGES;

    char* w = (char*)d_ws;
    auto alloc = [&](size_t bytes) -> char* {
        char* p = w;
        w += (bytes + 255) & ~(size_t)255;
        return p;
    };
    int*   gcount = (int*)  alloc((size_t)NB * 4);
    int*   gbase  = (int*)  alloc((size_t)NB * 4);
    int*   gcursor= (int*)  alloc((size_t)NB * 4);
    int*   rowptr = (int*)  alloc((size_t)(N_NODES + 1) * 4);
    float* dinv   = (float*)alloc((size_t)N_NODES * 4);
    float* zbuf   = (float*)alloc((size_t)N_GRAPHS * 64 * 4);
    // Arena (76.8 MB) in floats:
    //   A  [0,64N):    dense1 out bf16 (dinv*xW), dead after gather1;
    //                  partials alias here during k_gd3/k_poolF
    //   B  [64N,128N): gather1 out bf16 h1 (32 dims), input to k_gd2
    //   csr[128N,160N)
    //   B2 [160N,192N): k_gd2 out bf16 (64 dims), input to k_gd3
    float* arena = (float*)alloc((size_t)N_NODES * 192 * 4);
    float* A   = arena;
    float* B   = arena + (size_t)N_NODES * 64;
    int*   csr = (int*)(arena + (size_t)N_NODES * 128);
    float* B2  = arena + (size_t)N_NODES * 160;
    float* part0 = A;                               // [NBLK3][128]
    float* part1 = A + (size_t)NBLK3 * 128;         // [NBLK3][128]
    int*   pg0   = (int*)(A + (size_t)2 * NBLK3 * 128);
    int*   pg1   = pg0 + NBLK3;

    float* out    = (float*)d_out;
    float* out_mu = out + 10240000;
    float* out_lv = out + 10240000 + 4096;

    hipMemsetAsync(gcount, 0, (size_t)NB * 4, stream);

    // ---- CSR build (binned) ----
    k_binCount<<<NCHUNK, 512, 0, stream>>>(dstv, gcount);
    k_scanB<<<1, 512, 0, stream>>>(gcount, gbase, gcursor, rowptr);
    k_binA<<<NCHUNK, 512, 0, stream>>>(srcv, dstv, gcursor, csr);
    k_passB<<<NB, 512, 0, stream>>>(gbase, csr, rowptr, dinv);

    // ---- L1: dense -> dinv*xW bf16; gather w32 -> dinv*relu(...) bf16 ----
    k_dense4<64, 16, 0, 64, 0, false, true, true><<<N_NODES * 8 / 256, 256, 0, stream>>>(
        x, W1m, b1m, W1l, b1l, dinv, A);
    k_gatherB<5, true, true, true><<<(N_NODES + 63) / 64, 256, 0, stream>>>(
        rowptr, csr, (const unsigned*)A, dinv, b1m, b1l, B);

    // ---- L2 fused: gather w32 + dense 16->32 x2 -> B2 bf16 prescaled ----
    k_gd2<<<(N_NODES + 63) / 64, 256, 0, stream>>>(
        rowptr, csr, (const unsigned*)B, dinv, W2m, b2m, W2l, b2l, (unsigned*)B2);

    // ---- L3 fused: gather w64 + dense 32->64 x2 + pool partials (single dispatch) ----
    k_gd3<<<NBLK3, 256, 0, stream>>>(
        rowptr, csr, (const unsigned*)B2, dinv, W3m, b3m, W3l, b3l, batch,
        part0, part1, pg0, pg1);

    // ---- pool reduce + reparameterize (fused) ----
    k_poolF<<<N_GRAPHS, 128, 0, stream>>>(part0, part1, pg0, pg1, batch, eps,
                                          zbuf, out_mu, out_lv);

    // ---- decode ----
    k_decode<<<1250, 256, 0, stream>>>(zbuf, Wfc, bfc, out);
}

// Round 8
// 432.834 us; speedup vs baseline: 1.0710x; 1.0040x over previous
//
#include <hip/hip_runtime.h>
#include <hip/hip_bf16.h>

#define N_NODES 100000
#define N_EDGES 3200000
#define N_GRAPHS 64
#define NB 391                 // dst-buckets of 256 nodes (last has 160)
#define KCH 8192               // edges per binning block
#define NCHUNK ((N_EDGES + KCH - 1) / KCH)   // 391
#define MAXBKT 10240           // bucket capacity (mean 8192, sigma ~90)
#define NBLK3B 1563            // fused-L3 blocks (64 nodes each)

__device__ __forceinline__ void atomAddF(float* p, float v) {
    unsafeAtomicAdd(p, v);
}

// bf16x2 pack/unpack (RTNE via __float2bfloat16)
__device__ __forceinline__ float lo2f(unsigned u) { return __uint_as_float(u << 16); }
__device__ __forceinline__ float hi2f(unsigned u) { return __uint_as_float(u & 0xFFFF0000u); }
__device__ __forceinline__ unsigned pack2(float a, float b) {
    unsigned ha = __bfloat16_as_ushort(__float2bfloat16(a));
    unsigned hb = __bfloat16_as_ushort(__float2bfloat16(b));
    return ha | (hb << 16);
}

// ---------------- CSR build: binA-first with fixed-stride buckets ----------------
// binA scatters edges into bins[b*MAXBKT + pos] using raw global cursors (no
// pre-count pass -> k_binCount eliminated). scanB2 then scans the counts into
// gbase; passB compacts + node-sorts each bucket into the final csr.
__global__ __launch_bounds__(512) void k_binA(const int* __restrict__ src,
                                              const int* __restrict__ dst,
                                              int* __restrict__ gcursor,
                                              int* __restrict__ bins) {
    __shared__ int hist[512];
    __shared__ int rbase[512];
    hist[threadIdx.x] = 0;
    __syncthreads();
    int base = blockIdx.x * KCH;
    int cnt = min(KCH, N_EDGES - base);
    int pk[16];    // packed (dst&255)<<24 | src
    int meta[16];  // (b<<13) | pos, or -1   (static arrays: rule #20)
    #pragma unroll
    for (int i = 0; i < 16; ++i) {
        int idx = i * 512 + threadIdx.x;
        if (idx < cnt) {
            int d = dst[base + idx];
            int b = d >> 8;
            int pos = atomicAdd(&hist[b], 1);        // pos < 8192 -> 13 bits
            pk[i] = ((d & 255) << 24) | src[base + idx];
            meta[i] = (b << 13) | pos;
        } else {
            meta[i] = -1;
        }
    }
    __syncthreads();
    if (threadIdx.x < NB) {
        int v = hist[threadIdx.x];
        if (v > 0) rbase[threadIdx.x] = atomicAdd(&gcursor[threadIdx.x], v);
    }
    __syncthreads();
    #pragma unroll
    for (int i = 0; i < 16; ++i) {
        if (meta[i] >= 0) {
            int b = meta[i] >> 13;
            int pos = meta[i] & 8191;
            bins[(size_t)b * MAXBKT + rbase[b] + pos] = pk[i];
        }
    }
}

__global__ __launch_bounds__(512) void k_scanB2(const int* __restrict__ gcursor,
                                                int* __restrict__ gbase,
                                                int* __restrict__ rowptr) {
    __shared__ int s[512];
    int v = (threadIdx.x < NB) ? gcursor[threadIdx.x] : 0;
    s[threadIdx.x] = v;
    __syncthreads();
    for (int off = 1; off < 512; off <<= 1) {
        int t = (threadIdx.x >= off) ? s[threadIdx.x - off] : 0;
        __syncthreads();
        s[threadIdx.x] += t;
        __syncthreads();
    }
    if (threadIdx.x < NB) gbase[threadIdx.x] = s[threadIdx.x] - v;
    if (threadIdx.x == 0) rowptr[N_NODES] = N_EDGES;
}

__global__ __launch_bounds__(512) void k_passB(const int* __restrict__ gbase,
                                               const int* __restrict__ bins,
                                               int* __restrict__ csr,
                                               int* __restrict__ rowptr,
                                               float* __restrict__ dinv) {
    int b = blockIdx.x;
    int rb = gbase[b];
    int re = (b == NB - 1) ? N_EDGES : gbase[b + 1];
    int cnt = re - rb;
    int nbase = b << 8;
    int nn = min(nbase + 256, N_NODES) - nbase;
    __shared__ int stage[MAXBKT];   // 40 KB
    __shared__ int nhist[256];
    __shared__ int sc[256];
    __shared__ int ncur[256];
    for (int t = threadIdx.x; t < 256; t += 512) nhist[t] = 0;
    __syncthreads();
    const int* bsrc = bins + (size_t)b * MAXBKT;
    for (int j = threadIdx.x; j < cnt; j += 512) {
        int p = bsrc[j];
        stage[j] = p;
        atomicAdd(&nhist[((unsigned)p) >> 24], 1);
    }
    __syncthreads();
    if (threadIdx.x < 256) sc[threadIdx.x] = nhist[threadIdx.x];
    __syncthreads();
    for (int off = 1; off < 256; off <<= 1) {
        int t = (threadIdx.x < 256 && threadIdx.x >= off) ? sc[threadIdx.x - off] : 0;
        __syncthreads();
        if (threadIdx.x < 256) sc[threadIdx.x] += t;
        __syncthreads();
    }
    if (threadIdx.x < 256) {
        int e = sc[threadIdx.x] - nhist[threadIdx.x];
        ncur[threadIdx.x] = e;
        if (threadIdx.x < nn) {
            rowptr[nbase + threadIdx.x] = rb + e;
            dinv[nbase + threadIdx.x] = rsqrtf((float)nhist[threadIdx.x] + 1.0f);
        }
    }
    __syncthreads();
    for (int j = threadIdx.x; j < cnt; j += 512) {
        int p = stage[j];
        int slot = atomicAdd(&ncur[((unsigned)p) >> 24], 1);
        csr[rb + slot] = p;
    }
}

// -------- gather: out = di*(sum A'[s] + A'[n]) (+bias,relu) --------
template<int LOGW, bool BIAS_RELU, bool OB, bool PRE>
__global__ void __launch_bounds__(256) k_gatherB(
        const int* __restrict__ rowptr, const int* __restrict__ csr,
        const unsigned* __restrict__ in /* bf16x2 pairs, prescaled */,
        const float* __restrict__ dinv,
        const float* __restrict__ ba, const float* __restrict__ bb,
        void* __restrict__ out) {
    constexpr int W8 = (1 << LOGW) / 8;   // lanes per node (uint4 = 8 bf16)
    constexpr int NPB = 256 / W8;         // nodes per block
    int n = blockIdx.x * NPB + (threadIdx.x / W8);
    if (n >= N_NODES) return;
    int sub = threadIdx.x % W8;
    const uint4* in4 = (const uint4*)in;
    uint4 u = in4[(size_t)n * W8 + sub];              // self term A'[n]
    float a0 = lo2f(u.x), a1 = hi2f(u.x), a2 = lo2f(u.y), a3 = hi2f(u.y);
    float a4 = lo2f(u.z), a5 = hi2f(u.z), a6 = lo2f(u.w), a7 = hi2f(u.w);
    int j = rowptr[n], end = rowptr[n + 1];
    for (; j + 8 <= end; j += 8) {
        int s0 = csr[j] & 0xFFFFFF;
        int s1 = csr[j + 1] & 0xFFFFFF;
        int s2 = csr[j + 2] & 0xFFFFFF;
        int s3 = csr[j + 3] & 0xFFFFFF;
        int s4 = csr[j + 4] & 0xFFFFFF;
        int s5 = csr[j + 5] & 0xFFFFFF;
        int s6 = csr[j + 6] & 0xFFFFFF;
        int s7 = csr[j + 7] & 0xFFFFFF;
        uint4 v0 = in4[(size_t)s0 * W8 + sub];
        uint4 v1 = in4[(size_t)s1 * W8 + sub];
        uint4 v2 = in4[(size_t)s2 * W8 + sub];
        uint4 v3 = in4[(size_t)s3 * W8 + sub];
        uint4 v4 = in4[(size_t)s4 * W8 + sub];
        uint4 v5 = in4[(size_t)s5 * W8 + sub];
        uint4 v6 = in4[(size_t)s6 * W8 + sub];
        uint4 v7 = in4[(size_t)s7 * W8 + sub];
        a0 += ((lo2f(v0.x) + lo2f(v1.x)) + (lo2f(v2.x) + lo2f(v3.x)))
            + ((lo2f(v4.x) + lo2f(v5.x)) + (lo2f(v6.x) + lo2f(v7.x)));
        a1 += ((hi2f(v0.x) + hi2f(v1.x)) + (hi2f(v2.x) + hi2f(v3.x)))
            + ((hi2f(v4.x) + hi2f(v5.x)) + (hi2f(v6.x) + hi2f(v7.x)));
        a2 += ((lo2f(v0.y) + lo2f(v1.y)) + (lo2f(v2.y) + lo2f(v3.y)))
            + ((lo2f(v4.y) + lo2f(v5.y)) + (lo2f(v6.y) + lo2f(v7.y)));
        a3 += ((hi2f(v0.y) + hi2f(v1.y)) + (hi2f(v2.y) + hi2f(v3.y)))
            + ((hi2f(v4.y) + hi2f(v5.y)) + (hi2f(v6.y) + hi2f(v7.y)));
        a4 += ((lo2f(v0.z) + lo2f(v1.z)) + (lo2f(v2.z) + lo2f(v3.z)))
            + ((lo2f(v4.z) + lo2f(v5.z)) + (lo2f(v6.z) + lo2f(v7.z)));
        a5 += ((hi2f(v0.z) + hi2f(v1.z)) + (hi2f(v2.z) + hi2f(v3.z)))
            + ((hi2f(v4.z) + hi2f(v5.z)) + (hi2f(v6.z) + hi2f(v7.z)));
        a6 += ((lo2f(v0.w) + lo2f(v1.w)) + (lo2f(v2.w) + lo2f(v3.w)))
            + ((lo2f(v4.w) + lo2f(v5.w)) + (lo2f(v6.w) + lo2f(v7.w)));
        a7 += ((hi2f(v0.w) + hi2f(v1.w)) + (hi2f(v2.w) + hi2f(v3.w)))
            + ((hi2f(v4.w) + hi2f(v5.w)) + (hi2f(v6.w) + hi2f(v7.w)));
    }
    for (; j < end; ++j) {
        int s = csr[j] & 0xFFFFFF;
        uint4 v = in4[(size_t)s * W8 + sub];
        a0 += lo2f(v.x); a1 += hi2f(v.x);
        a2 += lo2f(v.y); a3 += hi2f(v.y);
        a4 += lo2f(v.z); a5 += hi2f(v.z);
        a6 += lo2f(v.w); a7 += hi2f(v.w);
    }
    float di = dinv[n];
    a0 *= di; a1 *= di; a2 *= di; a3 *= di;
    a4 *= di; a5 *= di; a6 *= di; a7 *= di;
    if (BIAS_RELU) {
        constexpr int H = (1 << LOGW) / 2;
        int d = sub * 8;                 // 8 | H for all instantiations
        const float* bp = (d < H) ? (ba + d) : (bb + d - H);
        a0 = fmaxf(a0 + bp[0], 0.0f);
        a1 = fmaxf(a1 + bp[1], 0.0f);
        a2 = fmaxf(a2 + bp[2], 0.0f);
        a3 = fmaxf(a3 + bp[3], 0.0f);
        a4 = fmaxf(a4 + bp[4], 0.0f);
        a5 = fmaxf(a5 + bp[5], 0.0f);
        a6 = fmaxf(a6 + bp[6], 0.0f);
        a7 = fmaxf(a7 + bp[7], 0.0f);
    }
    if (PRE) {  // pre-scale for the NEXT gather layer
        a0 *= di; a1 *= di; a2 *= di; a3 *= di;
        a4 *= di; a5 *= di; a6 *= di; a7 *= di;
    }
    if (OB) {
        ((uint4*)out)[(size_t)n * W8 + sub] =
            make_uint4(pack2(a0, a1), pack2(a2, a3), pack2(a4, a5), pack2(a6, a7));
    } else {
        constexpr int OUT4 = (1 << LOGW) / 4;
        float4* o4 = (float4*)out;
        o4[(size_t)n * OUT4 + sub * 2]     = make_float4(a0, a1, a2, a3);
        o4[(size_t)n * OUT4 + sub * 2 + 1] = make_float4(a4, a5, a6, a7);
    }
}

#define FMA4(A, W) \
    A.x = fmaf(r, W.x, A.x); A.y = fmaf(r, W.y, A.y); \
    A.z = fmaf(r, W.z, A.z); A.w = fmaf(r, W.w, A.w);

// ======== fused L2: gather(w32) + dense(16->32 x2, bias+relu) + prescaled bf16 out ========
__global__ void __launch_bounds__(256) k_gd2(
        const int* __restrict__ rowptr, const int* __restrict__ csr,
        const unsigned* __restrict__ in,     // B: bf16x2 h1, dinv-prescaled, 32 dims
        const float* __restrict__ dinv,
        const float* __restrict__ W2m, const float* __restrict__ b2m,
        const float* __restrict__ W2l, const float* __restrict__ b2l,
        unsigned* __restrict__ outB) {       // B2: 64 bf16 dims/node, prescaled
    __shared__ float sW[16 * 80];    // 5 KB: [16 k][chunk q: q*20 + 0..15]
    __shared__ float agg[64 * 37];   // 9.5 KB
    __shared__ float sbias[64];
    for (int t = threadIdx.x; t < 1024; t += 256) {
        int k = t >> 6, D = t & 63;
        float wv = (D < 32) ? W2m[k * 32 + D] : W2l[k * 32 + (D - 32)];
        sW[k * 80 + (D >> 4) * 20 + (D & 15)] = wv;
    }
    if (threadIdx.x < 64)
        sbias[threadIdx.x] = (threadIdx.x < 32) ? b2m[threadIdx.x]
                                                : b2l[threadIdx.x - 32];
    int ln  = threadIdx.x >> 2;
    int sub = threadIdx.x & 3;
    int n = blockIdx.x * 64 + ln;
    int nc = min(n, N_NODES - 1);        // clamp; invalid nodes never stored
    const uint4* in4 = (const uint4*)in;
    uint4 u = in4[(size_t)nc * 4 + sub];
    float a0 = lo2f(u.x), a1 = hi2f(u.x), a2 = lo2f(u.y), a3 = hi2f(u.y);
    float a4 = lo2f(u.z), a5 = hi2f(u.z), a6 = lo2f(u.w), a7 = hi2f(u.w);
    int j = rowptr[nc], end = rowptr[nc + 1];
    for (; j + 8 <= end; j += 8) {
        int s0 = csr[j] & 0xFFFFFF;
        int s1 = csr[j + 1] & 0xFFFFFF;
        int s2 = csr[j + 2] & 0xFFFFFF;
        int s3 = csr[j + 3] & 0xFFFFFF;
        int s4 = csr[j + 4] & 0xFFFFFF;
        int s5 = csr[j + 5] & 0xFFFFFF;
        int s6 = csr[j + 6] & 0xFFFFFF;
        int s7 = csr[j + 7] & 0xFFFFFF;
        uint4 v0 = in4[(size_t)s0 * 4 + sub];
        uint4 v1 = in4[(size_t)s1 * 4 + sub];
        uint4 v2 = in4[(size_t)s2 * 4 + sub];
        uint4 v3 = in4[(size_t)s3 * 4 + sub];
        uint4 v4 = in4[(size_t)s4 * 4 + sub];
        uint4 v5 = in4[(size_t)s5 * 4 + sub];
        uint4 v6 = in4[(size_t)s6 * 4 + sub];
        uint4 v7 = in4[(size_t)s7 * 4 + sub];
        a0 += ((lo2f(v0.x) + lo2f(v1.x)) + (lo2f(v2.x) + lo2f(v3.x)))
            + ((lo2f(v4.x) + lo2f(v5.x)) + (lo2f(v6.x) + lo2f(v7.x)));
        a1 += ((hi2f(v0.x) + hi2f(v1.x)) + (hi2f(v2.x) + hi2f(v3.x)))
            + ((hi2f(v4.x) + hi2f(v5.x)) + (hi2f(v6.x) + hi2f(v7.x)));
        a2 += ((lo2f(v0.y) + lo2f(v1.y)) + (lo2f(v2.y) + lo2f(v3.y)))
            + ((lo2f(v4.y) + lo2f(v5.y)) + (lo2f(v6.y) + lo2f(v7.y)));
        a3 += ((hi2f(v0.y) + hi2f(v1.y)) + (hi2f(v2.y) + hi2f(v3.y)))
            + ((hi2f(v4.y) + hi2f(v5.y)) + (hi2f(v6.y) + hi2f(v7.y)));
        a4 += ((lo2f(v0.z) + lo2f(v1.z)) + (lo2f(v2.z) + lo2f(v3.z)))
            + ((lo2f(v4.z) + lo2f(v5.z)) + (lo2f(v6.z) + lo2f(v7.z)));
        a5 += ((hi2f(v0.z) + hi2f(v1.z)) + (hi2f(v2.z) + hi2f(v3.z)))
            + ((hi2f(v4.z) + hi2f(v5.z)) + (hi2f(v6.z) + hi2f(v7.z)));
        a6 += ((lo2f(v0.w) + lo2f(v1.w)) + (lo2f(v2.w) + lo2f(v3.w)))
            + ((lo2f(v4.w) + lo2f(v5.w)) + (lo2f(v6.w) + lo2f(v7.w)));
        a7 += ((hi2f(v0.w) + hi2f(v1.w)) + (hi2f(v2.w) + hi2f(v3.w)))
            + ((hi2f(v4.w) + hi2f(v5.w)) + (hi2f(v6.w) + hi2f(v7.w)));
    }
    for (; j < end; ++j) {
        int s = csr[j] & 0xFFFFFF;
        uint4 v = in4[(size_t)s * 4 + sub];
        a0 += lo2f(v.x); a1 += hi2f(v.x);
        a2 += lo2f(v.y); a3 += hi2f(v.y);
        a4 += lo2f(v.z); a5 += hi2f(v.z);
        a6 += lo2f(v.w); a7 += hi2f(v.w);
    }
    float di = dinv[nc];
    a0 *= di; a1 *= di; a2 *= di; a3 *= di;
    a4 *= di; a5 *= di; a6 *= di; a7 *= di;
    {
        float* ap = &agg[ln * 37 + sub * 8];
        *(float4*)&ap[0] = make_float4(a0, a1, a2, a3);
        *(float4*)&ap[4] = make_float4(a4, a5, a6, a7);
    }
    __syncthreads();

    // ---- dense 16->32 x2 (bias + relu + dinv prescale), 16 outputs/thread ----
    int q = sub;                          // chunk: global dims [q*16, q*16+16)
    int Dbase = q * 16;
    int koff = (q >= 2) ? 16 : 0;         // log branch reads agg dims 16..31
    float4 c0 = *(const float4*)&sbias[Dbase];
    float4 c1 = *(const float4*)&sbias[Dbase + 4];
    float4 c2 = *(const float4*)&sbias[Dbase + 8];
    float4 c3 = *(const float4*)&sbias[Dbase + 12];
    const float* ag = &agg[ln * 37 + koff];
    const float* wq = &sW[q * 20];
    #pragma unroll
    for (int k = 0; k < 16; ++k) {
        float r = ag[k];
        const float* wr = &wq[k * 80];
        float4 w0 = *(const float4*)&wr[0];
        float4 w1 = *(const float4*)&wr[4];
        float4 w2 = *(const float4*)&wr[8];
        float4 w3 = *(const float4*)&wr[12];
        FMA4(c0, w0)
        FMA4(c1, w1)
        FMA4(c2, w2)
        FMA4(c3, w3)
    }
    c0.x = fmaxf(c0.x, 0.f) * di; c0.y = fmaxf(c0.y, 0.f) * di;
    c0.z = fmaxf(c0.z, 0.f) * di; c0.w = fmaxf(c0.w, 0.f) * di;
    c1.x = fmaxf(c1.x, 0.f) * di; c1.y = fmaxf(c1.y, 0.f) * di;
    c1.z = fmaxf(c1.z, 0.f) * di; c1.w = fmaxf(c1.w, 0.f) * di;
    c2.x = fmaxf(c2.x, 0.f) * di; c2.y = fmaxf(c2.y, 0.f) * di;
    c2.z = fmaxf(c2.z, 0.f) * di; c2.w = fmaxf(c2.w, 0.f) * di;
    c3.x = fmaxf(c3.x, 0.f) * di; c3.y = fmaxf(c3.y, 0.f) * di;
    c3.z = fmaxf(c3.z, 0.f) * di; c3.w = fmaxf(c3.w, 0.f) * di;
    if (n < N_NODES) {
        uint4* o4 = (uint4*)outB;
        o4[(size_t)n * 8 + q * 2] =
            make_uint4(pack2(c0.x, c0.y), pack2(c0.z, c0.w),
                       pack2(c1.x, c1.y), pack2(c1.z, c1.w));
        o4[(size_t)n * 8 + q * 2 + 1] =
            make_uint4(pack2(c2.x, c2.y), pack2(c2.z, c2.w),
                       pack2(c3.x, c3.y), pack2(c3.z, c3.w));
    }
}

// ======== fused L3 (512 thr, 64 nodes): gather(w64) + dense(32->64 x2) + pool-partials ========
// 512 threads = 64 nodes x 8 lanes. LDS ~52 KB -> 3 blocks/CU x 8 waves = 75%
// occupancy cap (vs 62.5% at 256-thr/32-node) + half the weight restaging.
// Static regs; weight chunks padded 16->20 (banks 20q mod 32 distinct).
__global__ void __launch_bounds__(512) void_marker();
__global__ void __launch_bounds__(512) k_gd3(
        const int* __restrict__ rowptr, const int* __restrict__ csr,
        const unsigned* __restrict__ in,     // B2: bf16x2, dinv-prescaled, 64 dims
        const float* __restrict__ dinv,
        const float* __restrict__ W3m, const float* __restrict__ b3m,
        const float* __restrict__ W3l, const float* __restrict__ b3l,
        const int* __restrict__ batch,
        float* __restrict__ part0, float* __restrict__ part1,
        int* __restrict__ pg0, int* __restrict__ pg1) {
    __shared__ float s_ali[64 * 132];     // 33.8 KB: sWall [32][160] (p2) / h3s [64][132] (p3)
    __shared__ float agg[64 * 68];        // 17.4 KB
    __shared__ float sbias[128];
    __shared__ int   sbatch[64];
    __shared__ int   ssplit;
    float* sWall = s_ali;                 // [32 k][chunk q: q*20 + 0..15]
    float* h3s   = s_ali;                 // [64 n][132]

    for (int t = threadIdx.x; t < 4096; t += 512) {
        int k = t >> 7, D = t & 127;
        float wv = (D < 64) ? W3m[k * 64 + D] : W3l[k * 64 + (D - 64)];
        sWall[k * 160 + (D >> 4) * 20 + (D & 15)] = wv;
    }
    if (threadIdx.x < 128)
        sbias[threadIdx.x] = (threadIdx.x < 64) ? b3m[threadIdx.x]
                                                : b3l[threadIdx.x - 64];
    int nbase = blockIdx.x * 64;
    if (threadIdx.x < 64)
        sbatch[threadIdx.x] = batch[min(nbase + (int)threadIdx.x, N_NODES - 1)];

    // ---- phase 1: gather ----
    int ln  = threadIdx.x >> 3;          // 0..63
    int sub = threadIdx.x & 7;
    int n = nbase + ln;
    int nc = min(n, N_NODES - 1);        // clamp; invalid nodes excluded from pool
    const uint4* in4 = (const uint4*)in;
    uint4 u = in4[(size_t)nc * 8 + sub];
    float a0 = lo2f(u.x), a1 = hi2f(u.x), a2 = lo2f(u.y), a3 = hi2f(u.y);
    float a4 = lo2f(u.z), a5 = hi2f(u.z), a6 = lo2f(u.w), a7 = hi2f(u.w);
    int j = rowptr[nc], end = rowptr[nc + 1];
    for (; j + 8 <= end; j += 8) {
        int s0 = csr[j] & 0xFFFFFF;
        int s1 = csr[j + 1] & 0xFFFFFF;
        int s2 = csr[j + 2] & 0xFFFFFF;
        int s3 = csr[j + 3] & 0xFFFFFF;
        int s4 = csr[j + 4] & 0xFFFFFF;
        int s5 = csr[j + 5] & 0xFFFFFF;
        int s6 = csr[j + 6] & 0xFFFFFF;
        int s7 = csr[j + 7] & 0xFFFFFF;
        uint4 v0 = in4[(size_t)s0 * 8 + sub];
        uint4 v1 = in4[(size_t)s1 * 8 + sub];
        uint4 v2 = in4[(size_t)s2 * 8 + sub];
        uint4 v3 = in4[(size_t)s3 * 8 + sub];
        uint4 v4 = in4[(size_t)s4 * 8 + sub];
        uint4 v5 = in4[(size_t)s5 * 8 + sub];
        uint4 v6 = in4[(size_t)s6 * 8 + sub];
        uint4 v7 = in4[(size_t)s7 * 8 + sub];
        a0 += ((lo2f(v0.x) + lo2f(v1.x)) + (lo2f(v2.x) + lo2f(v3.x)))
            + ((lo2f(v4.x) + lo2f(v5.x)) + (lo2f(v6.x) + lo2f(v7.x)));
        a1 += ((hi2f(v0.x) + hi2f(v1.x)) + (hi2f(v2.x) + hi2f(v3.x)))
            + ((hi2f(v4.x) + hi2f(v5.x)) + (hi2f(v6.x) + hi2f(v7.x)));
        a2 += ((lo2f(v0.y) + lo2f(v1.y)) + (lo2f(v2.y) + lo2f(v3.y)))
            + ((lo2f(v4.y) + lo2f(v5.y)) + (lo2f(v6.y) + lo2f(v7.y)));
        a3 += ((hi2f(v0.y) + hi2f(v1.y)) + (hi2f(v2.y) + hi2f(v3.y)))
            + ((hi2f(v4.y) + hi2f(v5.y)) + (hi2f(v6.y) + hi2f(v7.y)));
        a4 += ((lo2f(v0.z) + lo2f(v1.z)) + (lo2f(v2.z) + lo2f(v3.z)))
            + ((lo2f(v4.z) + lo2f(v5.z)) + (lo2f(v6.z) + lo2f(v7.z)));
        a5 += ((hi2f(v0.z) + hi2f(v1.z)) + (hi2f(v2.z) + hi2f(v3.z)))
            + ((hi2f(v4.z) + hi2f(v5.z)) + (hi2f(v6.z) + hi2f(v7.z)));
        a6 += ((lo2f(v0.w) + lo2f(v1.w)) + (lo2f(v2.w) + lo2f(v3.w)))
            + ((lo2f(v4.w) + lo2f(v5.w)) + (lo2f(v6.w) + lo2f(v7.w)));
        a7 += ((hi2f(v0.w) + hi2f(v1.w)) + (hi2f(v2.w) + hi2f(v3.w)))
            + ((hi2f(v4.w) + hi2f(v5.w)) + (hi2f(v6.w) + hi2f(v7.w)));
    }
    for (; j < end; ++j) {
        int s = csr[j] & 0xFFFFFF;
        uint4 v = in4[(size_t)s * 8 + sub];
        a0 += lo2f(v.x); a1 += hi2f(v.x);
        a2 += lo2f(v.y); a3 += hi2f(v.y);
        a4 += lo2f(v.z); a5 += hi2f(v.z);
        a6 += lo2f(v.w); a7 += hi2f(v.w);
    }
    float di = dinv[nc];
    a0 *= di; a1 *= di; a2 *= di; a3 *= di;
    a4 *= di; a5 *= di; a6 *= di; a7 *= di;
    {
        float* ap = &agg[ln * 68 + sub * 8];
        *(float4*)&ap[0] = make_float4(a0, a1, a2, a3);
        *(float4*)&ap[4] = make_float4(a4, a5, a6, a7);
    }
    if (threadIdx.x == 0) {               // segment split (<=2 graphs/block)
        int sp = 64;
        int ga = sbatch[0];
        for (int i = 1; i < 64; ++i)
            if (sbatch[i] != ga) { sp = i; break; }
        ssplit = sp;
    }
    __syncthreads();

    // ---- phase 2: dense 32->64 x2 (bias + relu), 16 outputs/thread, static regs ----
    int ln2 = threadIdx.x >> 3;           // 0..63
    int q   = threadIdx.x & 7;            // chunk: global dims [q*16, q*16+16)
    int Dbase = q * 16;
    int koff = (q >= 4) ? 32 : 0;         // log branch reads agg dims 32..63
    float4 c0 = *(const float4*)&sbias[Dbase];
    float4 c1 = *(const float4*)&sbias[Dbase + 4];
    float4 c2 = *(const float4*)&sbias[Dbase + 8];
    float4 c3 = *(const float4*)&sbias[Dbase + 12];
    const float* ag = &agg[ln2 * 68 + koff];
    const float* wq = &sWall[q * 20];
    #pragma unroll
    for (int k = 0; k < 32; ++k) {
        float r = ag[k];
        const float* wr = &wq[k * 160];
        float4 w0 = *(const float4*)&wr[0];
        float4 w1 = *(const float4*)&wr[4];
        float4 w2 = *(const float4*)&wr[8];
        float4 w3 = *(const float4*)&wr[12];
        FMA4(c0, w0)
        FMA4(c1, w1)
        FMA4(c2, w2)
        FMA4(c3, w3)
    }
    c0.x = fmaxf(c0.x, 0.f); c0.y = fmaxf(c0.y, 0.f);
    c0.z = fmaxf(c0.z, 0.f); c0.w = fmaxf(c0.w, 0.f);
    c1.x = fmaxf(c1.x, 0.f); c1.y = fmaxf(c1.y, 0.f);
    c1.z = fmaxf(c1.z, 0.f); c1.w = fmaxf(c1.w, 0.f);
    c2.x = fmaxf(c2.x, 0.f); c2.y = fmaxf(c2.y, 0.f);
    c2.z = fmaxf(c2.z, 0.f); c2.w = fmaxf(c2.w, 0.f);
    c3.x = fmaxf(c3.x, 0.f); c3.y = fmaxf(c3.y, 0.f);
    c3.z = fmaxf(c3.z, 0.f); c3.w = fmaxf(c3.w, 0.f);
    __syncthreads();   // sWall dead; h3s may now overwrite it

    // ---- phase 3: stage h3 ([64][132], static writes), reduce, write partials ----
    {
        float* hp = &h3s[ln2 * 132 + Dbase];
        *(float4*)&hp[0]  = c0;
        *(float4*)&hp[4]  = c1;
        *(float4*)&hp[8]  = c2;
        *(float4*)&hp[12] = c3;
    }
    __syncthreads();
    if (threadIdx.x < 256) {
        int d    = threadIdx.x & 127;
        int slot = threadIdx.x >> 7;      // 0: nodes [0,split)  1: [split,64)
        int ncap = min(64, N_NODES - nbase);
        int sp = min(ssplit, ncap);
        int s = slot ? sp : 0;
        int e = slot ? ncap : sp;
        float acc = 0.f;
        for (int nn = s; nn < e; ++nn)
            acc += h3s[nn * 132 + d];
        int blk = blockIdx.x;
        if (slot == 0) {
            part0[(size_t)blk * 128 + d] = acc;
            if (d == 0) pg0[blk] = sbatch[0];
        } else {
            part1[(size_t)blk * 128 + d] = acc;
            if (d == 0) pg1[blk] = (sp < ncap) ? sbatch[63] : -1;
        }
    }
}

// ---- pool reduce + reparameterize fused ----
__global__ void __launch_bounds__(128) k_poolF(
        const float* __restrict__ part0, const float* __restrict__ part1,
        const int* __restrict__ pg0, const int* __restrict__ pg1,
        const int* __restrict__ batch, const float* __restrict__ eps,
        float* __restrict__ zbuf, float* __restrict__ out_mu,
        float* __restrict__ out_lv) {
    int g = blockIdx.x;
    __shared__ int sb[2];
    __shared__ float spool[128];
    if (threadIdx.x < 2) {
        int target = g + threadIdx.x;
        int lo = 0, hi = N_NODES;
        while (lo < hi) {
            int mid = (lo + hi) >> 1;
            if (batch[mid] < target) lo = mid + 1; else hi = mid;
        }
        sb[threadIdx.x] = lo;
    }
    __syncthreads();
    int ns = sb[0], ne = sb[1];
    int d = threadIdx.x;
    float acc = 0.f;
    if (ne > ns) {
        int b0 = ns >> 6, b1 = (ne - 1) >> 6;     // 64 nodes per gd3 block
        for (int b = b0; b <= b1; ++b) {
            if (pg0[b] == g) acc += part0[(size_t)b * 128 + d];
            if (pg1[b] == g) acc += part1[(size_t)b * 128 + d];
        }
    }
    spool[d] = acc;
    __syncthreads();
    if (threadIdx.x < 64) {
        int k = threadIdx.x;
        float c = fmaxf((float)(ne - ns), 1.0f);
        float mu = spool[k] / c;
        float lv = spool[64 + k] / c;
        zbuf[k * 64 + g] = mu + eps[g * 64 + k] * __expf(0.5f * lv);  // zT[k][g]
        out_mu[g * 64 + k] = mu;
        out_lv[g * 64 + k] = lv;
    }
}

// ------- dense: two-branch matmul, 4 outputs/thread; optional dinv out-scale -------
template<int IN_W, int OUT_HALF, int A_OFF, int A_W, int B_OFF, bool BR, bool OB, bool DS>
__global__ void k_dense4(const float* __restrict__ in,
                         const float* __restrict__ Wa, const float* __restrict__ ba,
                         const float* __restrict__ Wb, const float* __restrict__ bb,
                         const float* __restrict__ dinv,
                         void* __restrict__ out) {
    __shared__ float sWa[A_W * OUT_HALF];
    __shared__ float sWb[A_W * OUT_HALF];
    __shared__ float sba[OUT_HALF];
    __shared__ float sbb[OUT_HALF];
    for (int t = threadIdx.x; t < A_W * OUT_HALF; t += 256) {
        sWa[t] = Wa[t];
        sWb[t] = Wb[t];
    }
    if (BR && threadIdx.x < OUT_HALF) {
        sba[threadIdx.x] = ba[threadIdx.x];
        sbb[threadIdx.x] = bb[threadIdx.x];
    }
    __syncthreads();
    constexpr int TPN = OUT_HALF / 2;            // threads per node
    int idx = blockIdx.x * 256 + threadIdx.x;    // exact grid: N*TPN
    int n = idx / TPN;
    int q = idx % TPN;
    bool isB = (q * 4) >= OUT_HALF;
    int dd = q * 4 - (isB ? OUT_HALF : 0);
    const float* sW = isB ? sWb : sWa;
    int ko = isB ? B_OFF : A_OFF;
    float4 acc;
    if (BR) {
        const float* bp = isB ? (sbb + dd) : (sba + dd);
        acc = make_float4(bp[0], bp[1], bp[2], bp[3]);
    } else {
        acc = make_float4(0.f, 0.f, 0.f, 0.f);
    }
    const float* row = in + (size_t)n * IN_W + ko;
    #pragma unroll
    for (int k = 0; k < A_W; ++k) {
        float r = row[k];
        float4 wv = *(const float4*)&sW[k * OUT_HALF + dd];
        acc.x = fmaf(r, wv.x, acc.x);
        acc.y = fmaf(r, wv.y, acc.y);
        acc.z = fmaf(r, wv.z, acc.z);
        acc.w = fmaf(r, wv.w, acc.w);
    }
    if (BR) {
        acc.x = fmaxf(acc.x, 0.f); acc.y = fmaxf(acc.y, 0.f);
        acc.z = fmaxf(acc.z, 0.f); acc.w = fmaxf(acc.w, 0.f);
    }
    if (DS) {
        float dn = dinv[n];
        acc.x *= dn; acc.y *= dn; acc.z *= dn; acc.w *= dn;
    }
    if (OB) {
        ((uint2*)out)[idx] = make_uint2(pack2(acc.x, acc.y), pack2(acc.z, acc.w));
    } else {
        ((float4*)out)[idx] = acc;
    }
}

// ---------------- decode: sigmoid(z @ Wfc + bfc) ----------------
__global__ void __launch_bounds__(256) k_decode(const float* __restrict__ zT,
                                                const float* __restrict__ Wfc,
                                                const float* __restrict__ bfc,
                                                float* __restrict__ out) {
    int j = (blockIdx.x >> 1) * 256 + threadIdx.x;
    int gh = (blockIdx.x & 1) * 32;            // graph-half base
    const float* zp = zT + gh;                 // uniform pointer
    float bias = bfc[j];
    float acc[32];
    #pragma unroll
    for (int g = 0; g < 32; ++g) acc[g] = bias;
    #pragma unroll 8
    for (int k = 0; k < 64; ++k) {
        float w = Wfc[(size_t)k * 160000 + j];
        #pragma unroll
        for (int g = 0; g < 32; ++g)
            acc[g] = fmaf(zp[k * 64 + g], w, acc[g]);
    }
    #pragma unroll
    for (int g = 0; g < 32; ++g) {
        float s = 1.0f / (1.0f + __expf(-acc[g]));
        out[(size_t)(gh + g) * 160000 + j] = s;
    }
}

extern "C" void kernel_launch(void* const* d_in, const int* in_sizes, int n_in,
                              void* d_out, int out_size, void* d_ws, size_t ws_size,
                              hipStream_t stream) {
    const float* x     = (const float*)d_in[0];
    const int*   ei    = (const int*)d_in[1];
    const int*   batch = (const int*)d_in[2];
    const float *W1m = (const float*)d_in[3],  *b1m = (const float*)d_in[4];
    const float *W2m = (const float*)d_in[5],  *b2m = (const float*)d_in[6];
    const float *W3m = (const float*)d_in[7],  *b3m = (const float*)d_in[8];
    const float *W1l = (const float*)d_in[9],  *b1l = (const float*)d_in[10];
    const float *W2l = (const float*)d_in[11], *b2l = (const float*)d_in[12];
    const float *W3l = (const float*)d_in[13], *b3l = (const float*)d_in[14];
    const float *Wfc = (const float*)d_in[15], *bfc = (const float*)d_in[16];
    const float *eps = (const float*)d_in[17];

    const int* srcv = ei;
    const int* dstv = ei + N_EDGES;

    char* w = (char*)d_ws;
    auto alloc = [&](size_t bytes) -> char* {
        char* p = w;
        w += (bytes + 255) & ~(size_t)255;
        return p;
    };
    int*   gbase  = (int*)  alloc((size_t)NB * 4);
    int*   gcursor= (int*)  alloc((size_t)NB * 4);
    int*   rowptr = (int*)  alloc((size_t)(N_NODES + 1) * 4);
    float* dinv   = (float*)alloc((size_t)N_NODES * 4);
    float* zbuf   = (float*)alloc((size_t)N_GRAPHS * 64 * 4);
    // Arena (76.8 MB) in floats:
    //   A  [0,64N):    fixed-stride bins (CSR phase, 16 MB) -> dense1 out bf16
    //                  -> dead after gather1 -> pool partials during k_gd3/poolF
    //   B  [64N,128N): gather1 out bf16 h1 (32 dims), input to k_gd2
    //   csr[128N,160N)
    //   B2 [160N,192N): k_gd2 out bf16 (64 dims), input to k_gd3
    float* arena = (float*)alloc((size_t)N_NODES * 192 * 4);
    float* A   = arena;
    float* B   = arena + (size_t)N_NODES * 64;
    int*   csr = (int*)(arena + (size_t)N_NODES * 128);
    float* B2  = arena + (size_t)N_NODES * 160;
    int*   bins  = (int*)A;                         // [NB][MAXBKT] (CSR phase only)
    float* part0 = A;                               // [NBLK3B][128]
    float* part1 = A + (size_t)NBLK3B * 128;        // [NBLK3B][128]
    int*   pg0   = (int*)(A + (size_t)2 * NBLK3B * 128);
    int*   pg1   = pg0 + NBLK3B;

    float* out    = (float*)d_out;
    float* out_mu = out + 10240000;
    float* out_lv = out + 10240000 + 4096;

    hipMemsetAsync(gcursor, 0, (size_t)NB * 4, stream);

    // ---- CSR build (binA-first, no count pass) ----
    k_binA<<<NCHUNK, 512, 0, stream>>>(srcv, dstv, gcursor, bins);
    k_scanB2<<<1, 512, 0, stream>>>(gcursor, gbase, rowptr);
    k_passB<<<NB, 512, 0, stream>>>(gbase, bins, csr, rowptr, dinv);

    // ---- L1: dense -> dinv*xW bf16; gather w32 -> dinv*relu(...) bf16 ----
    k_dense4<64, 16, 0, 64, 0, false, true, true><<<N_NODES * 8 / 256, 256, 0, stream>>>(
        x, W1m, b1m, W1l, b1l, dinv, A);
    k_gatherB<5, true, true, true><<<(N_NODES + 63) / 64, 256, 0, stream>>>(
        rowptr, csr, (const unsigned*)A, dinv, b1m, b1l, B);

    // ---- L2 fused: gather w32 + dense 16->32 x2 -> B2 bf16 prescaled ----
    k_gd2<<<(N_NODES + 63) / 64, 256, 0, stream>>>(
        rowptr, csr, (const unsigned*)B, dinv, W2m, b2m, W2l, b2l, (unsigned*)B2);

    // ---- L3 fused (512 thr / 64 nodes): gather w64 + dense 32->64 x2 + pool partials ----
    k_gd3<<<NBLK3B, 512, 0, stream>>>(
        rowptr, csr, (const unsigned*)B2, dinv, W3m, b3m, W3l, b3l, batch,
        part0, part1, pg0, pg1);

    // ---- pool reduce + reparameterize (fused) ----
    k_poolF<<<N_GRAPHS, 128, 0, stream>>>(part0, part1, pg0, pg1, batch, eps,
                                          zbuf, out_mu, out_lv);

    // ---- decode ----
    k_decode<<<1250, 256, 0, stream>>>(zbuf, Wfc, bfc, out);
}

// Round 9
// 424.699 us; speedup vs baseline: 1.0916x; 1.0192x over previous
//
#include <hip/hip_runtime.h>
#include <hip/hip_bf16.h>

#define N_NODES 100000
#define N_EDGES 3200000
#define N_GRAPHS 64
#define NB 391                 // dst-buckets of 256 nodes (last has 160)
#define KCH 8192               // edges per binning block
#define NCHUNK ((N_EDGES + KCH - 1) / KCH)   // 391
#define MAXBKT 10240           // bucket capacity (mean 8192, sigma ~90)
#define NBLK3 (N_NODES / 32)   // 3125 fused-L3 blocks (32 nodes each)

__device__ __forceinline__ void atomAddF(float* p, float v) {
    unsafeAtomicAdd(p, v);
}

// bf16x2 pack/unpack (RTNE via __float2bfloat16)
__device__ __forceinline__ float lo2f(unsigned u) { return __uint_as_float(u << 16); }
__device__ __forceinline__ float hi2f(unsigned u) { return __uint_as_float(u & 0xFFFF0000u); }
__device__ __forceinline__ unsigned pack2(float a, float b) {
    unsigned ha = __bfloat16_as_ushort(__float2bfloat16(a));
    unsigned hb = __bfloat16_as_ushort(__float2bfloat16(b));
    return ha | (hb << 16);
}

// ---------------- CSR build: binA-first with fixed-stride buckets ----------------
__global__ __launch_bounds__(512) void k_binA(const int* __restrict__ src,
                                              const int* __restrict__ dst,
                                              int* __restrict__ gcursor,
                                              int* __restrict__ bins) {
    __shared__ int hist[512];
    __shared__ int rbase[512];
    hist[threadIdx.x] = 0;
    __syncthreads();
    int base = blockIdx.x * KCH;
    int cnt = min(KCH, N_EDGES - base);
    int pk[16];    // packed (dst&255)<<24 | src
    int meta[16];  // (b<<13) | pos, or -1   (static arrays: rule #20)
    #pragma unroll
    for (int i = 0; i < 16; ++i) {
        int idx = i * 512 + threadIdx.x;
        if (idx < cnt) {
            int d = dst[base + idx];
            int b = d >> 8;
            int pos = atomicAdd(&hist[b], 1);        // pos < 8192 -> 13 bits
            pk[i] = ((d & 255) << 24) | src[base + idx];
            meta[i] = (b << 13) | pos;
        } else {
            meta[i] = -1;
        }
    }
    __syncthreads();
    if (threadIdx.x < NB) {
        int v = hist[threadIdx.x];
        if (v > 0) rbase[threadIdx.x] = atomicAdd(&gcursor[threadIdx.x], v);
    }
    __syncthreads();
    #pragma unroll
    for (int i = 0; i < 16; ++i) {
        if (meta[i] >= 0) {
            int b = meta[i] >> 13;
            int pos = meta[i] & 8191;
            bins[(size_t)b * MAXBKT + rbase[b] + pos] = pk[i];
        }
    }
}

__global__ __launch_bounds__(512) void k_scanB2(const int* __restrict__ gcursor,
                                                int* __restrict__ gbase,
                                                int* __restrict__ rowptr) {
    __shared__ int s[512];
    int v = (threadIdx.x < NB) ? gcursor[threadIdx.x] : 0;
    s[threadIdx.x] = v;
    __syncthreads();
    for (int off = 1; off < 512; off <<= 1) {
        int t = (threadIdx.x >= off) ? s[threadIdx.x - off] : 0;
        __syncthreads();
        s[threadIdx.x] += t;
        __syncthreads();
    }
    if (threadIdx.x < NB) gbase[threadIdx.x] = s[threadIdx.x] - v;
    if (threadIdx.x == 0) rowptr[N_NODES] = N_EDGES;
}

__global__ __launch_bounds__(512) void k_passB(const int* __restrict__ gbase,
                                               const int* __restrict__ bins,
                                               int* __restrict__ csr,
                                               int* __restrict__ rowptr,
                                               float* __restrict__ dinv) {
    int b = blockIdx.x;
    int rb = gbase[b];
    int re = (b == NB - 1) ? N_EDGES : gbase[b + 1];
    int cnt = re - rb;
    int nbase = b << 8;
    int nn = min(nbase + 256, N_NODES) - nbase;
    __shared__ int stage[MAXBKT];   // 40 KB
    __shared__ int nhist[256];
    __shared__ int sc[256];
    __shared__ int ncur[256];
    for (int t = threadIdx.x; t < 256; t += 512) nhist[t] = 0;
    __syncthreads();
    const int* bsrc = bins + (size_t)b * MAXBKT;
    for (int j = threadIdx.x; j < cnt; j += 512) {
        int p = bsrc[j];
        stage[j] = p;
        atomicAdd(&nhist[((unsigned)p) >> 24], 1);
    }
    __syncthreads();
    if (threadIdx.x < 256) sc[threadIdx.x] = nhist[threadIdx.x];
    __syncthreads();
    for (int off = 1; off < 256; off <<= 1) {
        int t = (threadIdx.x < 256 && threadIdx.x >= off) ? sc[threadIdx.x - off] : 0;
        __syncthreads();
        if (threadIdx.x < 256) sc[threadIdx.x] += t;
        __syncthreads();
    }
    if (threadIdx.x < 256) {
        int e = sc[threadIdx.x] - nhist[threadIdx.x];
        ncur[threadIdx.x] = e;
        if (threadIdx.x < nn) {
            rowptr[nbase + threadIdx.x] = rb + e;
            dinv[nbase + threadIdx.x] = rsqrtf((float)nhist[threadIdx.x] + 1.0f);
        }
    }
    __syncthreads();
    for (int j = threadIdx.x; j < cnt; j += 512) {
        int p = stage[j];
        int slot = atomicAdd(&ncur[((unsigned)p) >> 24], 1);
        csr[rb + slot] = p;
    }
}

// -------- gather: out = di*(sum A'[s] + A'[n]) (+bias,relu) --------
template<int LOGW, bool BIAS_RELU, bool OB, bool PRE>
__global__ void __launch_bounds__(256) k_gatherB(
        const int* __restrict__ rowptr, const int* __restrict__ csr,
        const unsigned* __restrict__ in /* bf16x2 pairs, prescaled */,
        const float* __restrict__ dinv,
        const float* __restrict__ ba, const float* __restrict__ bb,
        void* __restrict__ out) {
    constexpr int W8 = (1 << LOGW) / 8;   // lanes per node (uint4 = 8 bf16)
    constexpr int NPB = 256 / W8;         // nodes per block
    int n = blockIdx.x * NPB + (threadIdx.x / W8);
    if (n >= N_NODES) return;
    int sub = threadIdx.x % W8;
    const uint4* in4 = (const uint4*)in;
    uint4 u = in4[(size_t)n * W8 + sub];              // self term A'[n]
    float a0 = lo2f(u.x), a1 = hi2f(u.x), a2 = lo2f(u.y), a3 = hi2f(u.y);
    float a4 = lo2f(u.z), a5 = hi2f(u.z), a6 = lo2f(u.w), a7 = hi2f(u.w);
    int j = rowptr[n], end = rowptr[n + 1];
    for (; j + 8 <= end; j += 8) {
        int s0 = csr[j] & 0xFFFFFF;
        int s1 = csr[j + 1] & 0xFFFFFF;
        int s2 = csr[j + 2] & 0xFFFFFF;
        int s3 = csr[j + 3] & 0xFFFFFF;
        int s4 = csr[j + 4] & 0xFFFFFF;
        int s5 = csr[j + 5] & 0xFFFFFF;
        int s6 = csr[j + 6] & 0xFFFFFF;
        int s7 = csr[j + 7] & 0xFFFFFF;
        uint4 v0 = in4[(size_t)s0 * W8 + sub];
        uint4 v1 = in4[(size_t)s1 * W8 + sub];
        uint4 v2 = in4[(size_t)s2 * W8 + sub];
        uint4 v3 = in4[(size_t)s3 * W8 + sub];
        uint4 v4 = in4[(size_t)s4 * W8 + sub];
        uint4 v5 = in4[(size_t)s5 * W8 + sub];
        uint4 v6 = in4[(size_t)s6 * W8 + sub];
        uint4 v7 = in4[(size_t)s7 * W8 + sub];
        a0 += ((lo2f(v0.x) + lo2f(v1.x)) + (lo2f(v2.x) + lo2f(v3.x)))
            + ((lo2f(v4.x) + lo2f(v5.x)) + (lo2f(v6.x) + lo2f(v7.x)));
        a1 += ((hi2f(v0.x) + hi2f(v1.x)) + (hi2f(v2.x) + hi2f(v3.x)))
            + ((hi2f(v4.x) + hi2f(v5.x)) + (hi2f(v6.x) + hi2f(v7.x)));
        a2 += ((lo2f(v0.y) + lo2f(v1.y)) + (lo2f(v2.y) + lo2f(v3.y)))
            + ((lo2f(v4.y) + lo2f(v5.y)) + (lo2f(v6.y) + lo2f(v7.y)));
        a3 += ((hi2f(v0.y) + hi2f(v1.y)) + (hi2f(v2.y) + hi2f(v3.y)))
            + ((hi2f(v4.y) + hi2f(v5.y)) + (hi2f(v6.y) + hi2f(v7.y)));
        a4 += ((lo2f(v0.z) + lo2f(v1.z)) + (lo2f(v2.z) + lo2f(v3.z)))
            + ((lo2f(v4.z) + lo2f(v5.z)) + (lo2f(v6.z) + lo2f(v7.z)));
        a5 += ((hi2f(v0.z) + hi2f(v1.z)) + (hi2f(v2.z) + hi2f(v3.z)))
            + ((hi2f(v4.z) + hi2f(v5.z)) + (hi2f(v6.z) + hi2f(v7.z)));
        a6 += ((lo2f(v0.w) + lo2f(v1.w)) + (lo2f(v2.w) + lo2f(v3.w)))
            + ((lo2f(v4.w) + lo2f(v5.w)) + (lo2f(v6.w) + lo2f(v7.w)));
        a7 += ((hi2f(v0.w) + hi2f(v1.w)) + (hi2f(v2.w) + hi2f(v3.w)))
            + ((hi2f(v4.w) + hi2f(v5.w)) + (hi2f(v6.w) + hi2f(v7.w)));
    }
    for (; j < end; ++j) {
        int s = csr[j] & 0xFFFFFF;
        uint4 v = in4[(size_t)s * W8 + sub];
        a0 += lo2f(v.x); a1 += hi2f(v.x);
        a2 += lo2f(v.y); a3 += hi2f(v.y);
        a4 += lo2f(v.z); a5 += hi2f(v.z);
        a6 += lo2f(v.w); a7 += hi2f(v.w);
    }
    float di = dinv[n];
    a0 *= di; a1 *= di; a2 *= di; a3 *= di;
    a4 *= di; a5 *= di; a6 *= di; a7 *= di;
    if (BIAS_RELU) {
        constexpr int H = (1 << LOGW) / 2;
        int d = sub * 8;                 // 8 | H for all instantiations
        const float* bp = (d < H) ? (ba + d) : (bb + d - H);
        a0 = fmaxf(a0 + bp[0], 0.0f);
        a1 = fmaxf(a1 + bp[1], 0.0f);
        a2 = fmaxf(a2 + bp[2], 0.0f);
        a3 = fmaxf(a3 + bp[3], 0.0f);
        a4 = fmaxf(a4 + bp[4], 0.0f);
        a5 = fmaxf(a5 + bp[5], 0.0f);
        a6 = fmaxf(a6 + bp[6], 0.0f);
        a7 = fmaxf(a7 + bp[7], 0.0f);
    }
    if (PRE) {  // pre-scale for the NEXT gather layer
        a0 *= di; a1 *= di; a2 *= di; a3 *= di;
        a4 *= di; a5 *= di; a6 *= di; a7 *= di;
    }
    if (OB) {
        ((uint4*)out)[(size_t)n * W8 + sub] =
            make_uint4(pack2(a0, a1), pack2(a2, a3), pack2(a4, a5), pack2(a6, a7));
    } else {
        constexpr int OUT4 = (1 << LOGW) / 4;
        float4* o4 = (float4*)out;
        o4[(size_t)n * OUT4 + sub * 2]     = make_float4(a0, a1, a2, a3);
        o4[(size_t)n * OUT4 + sub * 2 + 1] = make_float4(a4, a5, a6, a7);
    }
}

#define FMA4(A, W) \
    A.x = fmaf(r, W.x, A.x); A.y = fmaf(r, W.y, A.y); \
    A.z = fmaf(r, W.z, A.z); A.w = fmaf(r, W.w, A.w);

// ======== fused L2: gather(w32) + dense(16->32 x2, bias+relu) + prescaled bf16 out ========
__global__ void __launch_bounds__(256) k_gd2(
        const int* __restrict__ rowptr, const int* __restrict__ csr,
        const unsigned* __restrict__ in,     // B: bf16x2 h1, dinv-prescaled, 32 dims
        const float* __restrict__ dinv,
        const float* __restrict__ W2m, const float* __restrict__ b2m,
        const float* __restrict__ W2l, const float* __restrict__ b2l,
        unsigned* __restrict__ outB) {       // B2: 64 bf16 dims/node, prescaled
    __shared__ float sW[16 * 80];    // 5 KB: [16 k][chunk q: q*20 + 0..15]
    __shared__ float agg[64 * 37];   // 9.5 KB
    __shared__ float sbias[64];
    for (int t = threadIdx.x; t < 1024; t += 256) {
        int k = t >> 6, D = t & 63;
        float wv = (D < 32) ? W2m[k * 32 + D] : W2l[k * 32 + (D - 32)];
        sW[k * 80 + (D >> 4) * 20 + (D & 15)] = wv;
    }
    if (threadIdx.x < 64)
        sbias[threadIdx.x] = (threadIdx.x < 32) ? b2m[threadIdx.x]
                                                : b2l[threadIdx.x - 32];
    int ln  = threadIdx.x >> 2;
    int sub = threadIdx.x & 3;
    int n = blockIdx.x * 64 + ln;
    int nc = min(n, N_NODES - 1);        // clamp; invalid nodes never stored
    const uint4* in4 = (const uint4*)in;
    uint4 u = in4[(size_t)nc * 4 + sub];
    float a0 = lo2f(u.x), a1 = hi2f(u.x), a2 = lo2f(u.y), a3 = hi2f(u.y);
    float a4 = lo2f(u.z), a5 = hi2f(u.z), a6 = lo2f(u.w), a7 = hi2f(u.w);
    int j = rowptr[nc], end = rowptr[nc + 1];
    for (; j + 8 <= end; j += 8) {
        int s0 = csr[j] & 0xFFFFFF;
        int s1 = csr[j + 1] & 0xFFFFFF;
        int s2 = csr[j + 2] & 0xFFFFFF;
        int s3 = csr[j + 3] & 0xFFFFFF;
        int s4 = csr[j + 4] & 0xFFFFFF;
        int s5 = csr[j + 5] & 0xFFFFFF;
        int s6 = csr[j + 6] & 0xFFFFFF;
        int s7 = csr[j + 7] & 0xFFFFFF;
        uint4 v0 = in4[(size_t)s0 * 4 + sub];
        uint4 v1 = in4[(size_t)s1 * 4 + sub];
        uint4 v2 = in4[(size_t)s2 * 4 + sub];
        uint4 v3 = in4[(size_t)s3 * 4 + sub];
        uint4 v4 = in4[(size_t)s4 * 4 + sub];
        uint4 v5 = in4[(size_t)s5 * 4 + sub];
        uint4 v6 = in4[(size_t)s6 * 4 + sub];
        uint4 v7 = in4[(size_t)s7 * 4 + sub];
        a0 += ((lo2f(v0.x) + lo2f(v1.x)) + (lo2f(v2.x) + lo2f(v3.x)))
            + ((lo2f(v4.x) + lo2f(v5.x)) + (lo2f(v6.x) + lo2f(v7.x)));
        a1 += ((hi2f(v0.x) + hi2f(v1.x)) + (hi2f(v2.x) + hi2f(v3.x)))
            + ((hi2f(v4.x) + hi2f(v5.x)) + (hi2f(v6.x) + hi2f(v7.x)));
        a2 += ((lo2f(v0.y) + lo2f(v1.y)) + (lo2f(v2.y) + lo2f(v3.y)))
            + ((lo2f(v4.y) + lo2f(v5.y)) + (lo2f(v6.y) + lo2f(v7.y)));
        a3 += ((hi2f(v0.y) + hi2f(v1.y)) + (hi2f(v2.y) + hi2f(v3.y)))
            + ((hi2f(v4.y) + hi2f(v5.y)) + (hi2f(v6.y) + hi2f(v7.y)));
        a4 += ((lo2f(v0.z) + lo2f(v1.z)) + (lo2f(v2.z) + lo2f(v3.z)))
            + ((lo2f(v4.z) + lo2f(v5.z)) + (lo2f(v6.z) + lo2f(v7.z)));
        a5 += ((hi2f(v0.z) + hi2f(v1.z)) + (hi2f(v2.z) + hi2f(v3.z)))
            + ((hi2f(v4.z) + hi2f(v5.z)) + (hi2f(v6.z) + hi2f(v7.z)));
        a6 += ((lo2f(v0.w) + lo2f(v1.w)) + (lo2f(v2.w) + lo2f(v3.w)))
            + ((lo2f(v4.w) + lo2f(v5.w)) + (lo2f(v6.w) + lo2f(v7.w)));
        a7 += ((hi2f(v0.w) + hi2f(v1.w)) + (hi2f(v2.w) + hi2f(v3.w)))
            + ((hi2f(v4.w) + hi2f(v5.w)) + (hi2f(v6.w) + hi2f(v7.w)));
    }
    for (; j < end; ++j) {
        int s = csr[j] & 0xFFFFFF;
        uint4 v = in4[(size_t)s * 4 + sub];
        a0 += lo2f(v.x); a1 += hi2f(v.x);
        a2 += lo2f(v.y); a3 += hi2f(v.y);
        a4 += lo2f(v.z); a5 += hi2f(v.z);
        a6 += lo2f(v.w); a7 += hi2f(v.w);
    }
    float di = dinv[nc];
    a0 *= di; a1 *= di; a2 *= di; a3 *= di;
    a4 *= di; a5 *= di; a6 *= di; a7 *= di;
    {
        float* ap = &agg[ln * 37 + sub * 8];
        *(float4*)&ap[0] = make_float4(a0, a1, a2, a3);
        *(float4*)&ap[4] = make_float4(a4, a5, a6, a7);
    }
    __syncthreads();

    // ---- dense 16->32 x2 (bias + relu + dinv prescale), 16 outputs/thread ----
    int q = sub;                          // chunk: global dims [q*16, q*16+16)
    int Dbase = q * 16;
    int koff = (q >= 2) ? 16 : 0;         // log branch reads agg dims 16..31
    float4 c0 = *(const float4*)&sbias[Dbase];
    float4 c1 = *(const float4*)&sbias[Dbase + 4];
    float4 c2 = *(const float4*)&sbias[Dbase + 8];
    float4 c3 = *(const float4*)&sbias[Dbase + 12];
    const float* ag = &agg[ln * 37 + koff];
    const float* wq = &sW[q * 20];
    #pragma unroll
    for (int k = 0; k < 16; ++k) {
        float r = ag[k];
        const float* wr = &wq[k * 80];
        float4 w0 = *(const float4*)&wr[0];
        float4 w1 = *(const float4*)&wr[4];
        float4 w2 = *(const float4*)&wr[8];
        float4 w3 = *(const float4*)&wr[12];
        FMA4(c0, w0)
        FMA4(c1, w1)
        FMA4(c2, w2)
        FMA4(c3, w3)
    }
    c0.x = fmaxf(c0.x, 0.f) * di; c0.y = fmaxf(c0.y, 0.f) * di;
    c0.z = fmaxf(c0.z, 0.f) * di; c0.w = fmaxf(c0.w, 0.f) * di;
    c1.x = fmaxf(c1.x, 0.f) * di; c1.y = fmaxf(c1.y, 0.f) * di;
    c1.z = fmaxf(c1.z, 0.f) * di; c1.w = fmaxf(c1.w, 0.f) * di;
    c2.x = fmaxf(c2.x, 0.f) * di; c2.y = fmaxf(c2.y, 0.f) * di;
    c2.z = fmaxf(c2.z, 0.f) * di; c2.w = fmaxf(c2.w, 0.f) * di;
    c3.x = fmaxf(c3.x, 0.f) * di; c3.y = fmaxf(c3.y, 0.f) * di;
    c3.z = fmaxf(c3.z, 0.f) * di; c3.w = fmaxf(c3.w, 0.f) * di;
    if (n < N_NODES) {
        uint4* o4 = (uint4*)outB;
        o4[(size_t)n * 8 + q * 2] =
            make_uint4(pack2(c0.x, c0.y), pack2(c0.z, c0.w),
                       pack2(c1.x, c1.y), pack2(c1.z, c1.w));
        o4[(size_t)n * 8 + q * 2 + 1] =
            make_uint4(pack2(c2.x, c2.y), pack2(c2.z, c2.w),
                       pack2(c3.x, c3.y), pack2(c3.z, c3.w));
    }
}

// ======== fused L3 (256 thr, 32 nodes — proven optimum): gather(w64) + dense + pool-partials ========
// R7's 512-thr/64-node variant REGRESSED (94us, occ 35%): straggler effect
// scales with nodes/block and phase-3 went half-idle. Keep 256/32.
__global__ void __launch_bounds__(256) k_gd3(
        const int* __restrict__ rowptr, const int* __restrict__ csr,
        const unsigned* __restrict__ in,     // B2: bf16x2, dinv-prescaled, 64 dims
        const float* __restrict__ dinv,
        const float* __restrict__ W3m, const float* __restrict__ b3m,
        const float* __restrict__ W3l, const float* __restrict__ b3l,
        const int* __restrict__ batch,
        float* __restrict__ part0, float* __restrict__ part1,
        int* __restrict__ pg0, int* __restrict__ pg1) {
    __shared__ float s_ali[32 * 160];     // 20.5 KB: sWall (p2) / h3s (p3)
    __shared__ float agg[32 * 68];        // 8.7 KB
    __shared__ float sbias[128];
    __shared__ int   sbatch[32];
    __shared__ int   ssplit;
    float* sWall = s_ali;                 // [32 k][chunk q: q*20 + 0..15]
    float* h3s   = s_ali;                 // [32 n][132]

    for (int t = threadIdx.x; t < 4096; t += 256) {
        int k = t >> 7, D = t & 127;
        float wv = (D < 64) ? W3m[k * 64 + D] : W3l[k * 64 + (D - 64)];
        sWall[k * 160 + (D >> 4) * 20 + (D & 15)] = wv;
    }
    if (threadIdx.x < 128)
        sbias[threadIdx.x] = (threadIdx.x < 64) ? b3m[threadIdx.x]
                                                : b3l[threadIdx.x - 64];
    int nbase = blockIdx.x * 32;
    if (threadIdx.x < 32) sbatch[threadIdx.x] = batch[nbase + threadIdx.x];

    // ---- phase 1: gather ----
    int ln  = threadIdx.x >> 3;
    int sub = threadIdx.x & 7;
    int n = nbase + ln;
    const uint4* in4 = (const uint4*)in;
    uint4 u = in4[(size_t)n * 8 + sub];
    float a0 = lo2f(u.x), a1 = hi2f(u.x), a2 = lo2f(u.y), a3 = hi2f(u.y);
    float a4 = lo2f(u.z), a5 = hi2f(u.z), a6 = lo2f(u.w), a7 = hi2f(u.w);
    int j = rowptr[n], end = rowptr[n + 1];
    for (; j + 8 <= end; j += 8) {
        int s0 = csr[j] & 0xFFFFFF;
        int s1 = csr[j + 1] & 0xFFFFFF;
        int s2 = csr[j + 2] & 0xFFFFFF;
        int s3 = csr[j + 3] & 0xFFFFFF;
        int s4 = csr[j + 4] & 0xFFFFFF;
        int s5 = csr[j + 5] & 0xFFFFFF;
        int s6 = csr[j + 6] & 0xFFFFFF;
        int s7 = csr[j + 7] & 0xFFFFFF;
        uint4 v0 = in4[(size_t)s0 * 8 + sub];
        uint4 v1 = in4[(size_t)s1 * 8 + sub];
        uint4 v2 = in4[(size_t)s2 * 8 + sub];
        uint4 v3 = in4[(size_t)s3 * 8 + sub];
        uint4 v4 = in4[(size_t)s4 * 8 + sub];
        uint4 v5 = in4[(size_t)s5 * 8 + sub];
        uint4 v6 = in4[(size_t)s6 * 8 + sub];
        uint4 v7 = in4[(size_t)s7 * 8 + sub];
        a0 += ((lo2f(v0.x) + lo2f(v1.x)) + (lo2f(v2.x) + lo2f(v3.x)))
            + ((lo2f(v4.x) + lo2f(v5.x)) + (lo2f(v6.x) + lo2f(v7.x)));
        a1 += ((hi2f(v0.x) + hi2f(v1.x)) + (hi2f(v2.x) + hi2f(v3.x)))
            + ((hi2f(v4.x) + hi2f(v5.x)) + (hi2f(v6.x) + hi2f(v7.x)));
        a2 += ((lo2f(v0.y) + lo2f(v1.y)) + (lo2f(v2.y) + lo2f(v3.y)))
            + ((lo2f(v4.y) + lo2f(v5.y)) + (lo2f(v6.y) + lo2f(v7.y)));
        a3 += ((hi2f(v0.y) + hi2f(v1.y)) + (hi2f(v2.y) + hi2f(v3.y)))
            + ((hi2f(v4.y) + hi2f(v5.y)) + (hi2f(v6.y) + hi2f(v7.y)));
        a4 += ((lo2f(v0.z) + lo2f(v1.z)) + (lo2f(v2.z) + lo2f(v3.z)))
            + ((lo2f(v4.z) + lo2f(v5.z)) + (lo2f(v6.z) + lo2f(v7.z)));
        a5 += ((hi2f(v0.z) + hi2f(v1.z)) + (hi2f(v2.z) + hi2f(v3.z)))
            + ((hi2f(v4.z) + hi2f(v5.z)) + (hi2f(v6.z) + hi2f(v7.z)));
        a6 += ((lo2f(v0.w) + lo2f(v1.w)) + (lo2f(v2.w) + lo2f(v3.w)))
            + ((lo2f(v4.w) + lo2f(v5.w)) + (lo2f(v6.w) + lo2f(v7.w)));
        a7 += ((hi2f(v0.w) + hi2f(v1.w)) + (hi2f(v2.w) + hi2f(v3.w)))
            + ((hi2f(v4.w) + hi2f(v5.w)) + (hi2f(v6.w) + hi2f(v7.w)));
    }
    for (; j < end; ++j) {
        int s = csr[j] & 0xFFFFFF;
        uint4 v = in4[(size_t)s * 8 + sub];
        a0 += lo2f(v.x); a1 += hi2f(v.x);
        a2 += lo2f(v.y); a3 += hi2f(v.y);
        a4 += lo2f(v.z); a5 += hi2f(v.z);
        a6 += lo2f(v.w); a7 += hi2f(v.w);
    }
    float di = dinv[n];
    a0 *= di; a1 *= di; a2 *= di; a3 *= di;
    a4 *= di; a5 *= di; a6 *= di; a7 *= di;
    {
        float* ap = &agg[ln * 68 + sub * 8];
        *(float4*)&ap[0] = make_float4(a0, a1, a2, a3);
        *(float4*)&ap[4] = make_float4(a4, a5, a6, a7);
    }
    if (threadIdx.x == 0) {               // segment split (<=2 graphs/block)
        int sp = 32;
        int ga = sbatch[0];
        for (int i = 1; i < 32; ++i)
            if (sbatch[i] != ga) { sp = i; break; }
        ssplit = sp;
    }
    __syncthreads();

    // ---- phase 2: dense 32->64 x2 (bias + relu), 16 outputs/thread, static regs ----
    int ln2 = threadIdx.x >> 3;
    int q   = threadIdx.x & 7;            // chunk: global dims [q*16, q*16+16)
    int Dbase = q * 16;
    int koff = (q >= 4) ? 32 : 0;         // log branch reads agg dims 32..63
    float4 c0 = *(const float4*)&sbias[Dbase];
    float4 c1 = *(const float4*)&sbias[Dbase + 4];
    float4 c2 = *(const float4*)&sbias[Dbase + 8];
    float4 c3 = *(const float4*)&sbias[Dbase + 12];
    const float* ag = &agg[ln2 * 68 + koff];
    const float* wq = &sWall[q * 20];
    #pragma unroll
    for (int k = 0; k < 32; ++k) {
        float r = ag[k];
        const float* wr = &wq[k * 160];
        float4 w0 = *(const float4*)&wr[0];
        float4 w1 = *(const float4*)&wr[4];
        float4 w2 = *(const float4*)&wr[8];
        float4 w3 = *(const float4*)&wr[12];
        FMA4(c0, w0)
        FMA4(c1, w1)
        FMA4(c2, w2)
        FMA4(c3, w3)
    }
    c0.x = fmaxf(c0.x, 0.f); c0.y = fmaxf(c0.y, 0.f);
    c0.z = fmaxf(c0.z, 0.f); c0.w = fmaxf(c0.w, 0.f);
    c1.x = fmaxf(c1.x, 0.f); c1.y = fmaxf(c1.y, 0.f);
    c1.z = fmaxf(c1.z, 0.f); c1.w = fmaxf(c1.w, 0.f);
    c2.x = fmaxf(c2.x, 0.f); c2.y = fmaxf(c2.y, 0.f);
    c2.z = fmaxf(c2.z, 0.f); c2.w = fmaxf(c2.w, 0.f);
    c3.x = fmaxf(c3.x, 0.f); c3.y = fmaxf(c3.y, 0.f);
    c3.z = fmaxf(c3.z, 0.f); c3.w = fmaxf(c3.w, 0.f);
    __syncthreads();   // sWall dead; h3s may now overwrite it

    // ---- phase 3: stage h3 (linear [32][132], static writes), write partials ----
    {
        float* hp = &h3s[ln2 * 132 + Dbase];
        *(float4*)&hp[0]  = c0;
        *(float4*)&hp[4]  = c1;
        *(float4*)&hp[8]  = c2;
        *(float4*)&hp[12] = c3;
    }
    __syncthreads();
    {
        int d    = threadIdx.x & 127;
        int slot = threadIdx.x >> 7;      // 0: nodes [0,split)  1: [split,32)
        int sp = ssplit;
        int s = slot ? sp : 0;
        int e = slot ? 32 : sp;
        float acc = 0.f;
        for (int nn = s; nn < e; ++nn)
            acc += h3s[nn * 132 + d];
        int blk = blockIdx.x;
        if (slot == 0) {
            part0[(size_t)blk * 128 + d] = acc;
            if (d == 0) pg0[blk] = sbatch[0];
        } else {
            part1[(size_t)blk * 128 + d] = acc;
            if (d == 0) pg1[blk] = (sp < 32) ? sbatch[31] : -1;
        }
    }
}

// ---- pool reduce + reparameterize fused ----
__global__ void __launch_bounds__(128) k_poolF(
        const float* __restrict__ part0, const float* __restrict__ part1,
        const int* __restrict__ pg0, const int* __restrict__ pg1,
        const int* __restrict__ batch, const float* __restrict__ eps,
        float* __restrict__ zbuf, float* __restrict__ out_mu,
        float* __restrict__ out_lv) {
    int g = blockIdx.x;
    __shared__ int sb[2];
    __shared__ float spool[128];
    if (threadIdx.x < 2) {
        int target = g + threadIdx.x;
        int lo = 0, hi = N_NODES;
        while (lo < hi) {
            int mid = (lo + hi) >> 1;
            if (batch[mid] < target) lo = mid + 1; else hi = mid;
        }
        sb[threadIdx.x] = lo;
    }
    __syncthreads();
    int ns = sb[0], ne = sb[1];
    int d = threadIdx.x;
    float acc = 0.f;
    if (ne > ns) {
        int b0 = ns >> 5, b1 = (ne - 1) >> 5;     // 32 nodes per gd3 block
        for (int b = b0; b <= b1; ++b) {
            if (pg0[b] == g) acc += part0[(size_t)b * 128 + d];
            if (pg1[b] == g) acc += part1[(size_t)b * 128 + d];
        }
    }
    spool[d] = acc;
    __syncthreads();
    if (threadIdx.x < 64) {
        int k = threadIdx.x;
        float c = fmaxf((float)(ne - ns), 1.0f);
        float mu = spool[k] / c;
        float lv = spool[64 + k] / c;
        zbuf[k * 64 + g] = mu + eps[g * 64 + k] * __expf(0.5f * lv);  // zT[k][g]
        out_mu[g * 64 + k] = mu;
        out_lv[g * 64 + k] = lv;
    }
}

// ------- dense: two-branch matmul, 4 outputs/thread; optional dinv out-scale -------
template<int IN_W, int OUT_HALF, int A_OFF, int A_W, int B_OFF, bool BR, bool OB, bool DS>
__global__ void k_dense4(const float* __restrict__ in,
                         const float* __restrict__ Wa, const float* __restrict__ ba,
                         const float* __restrict__ Wb, const float* __restrict__ bb,
                         const float* __restrict__ dinv,
                         void* __restrict__ out) {
    __shared__ float sWa[A_W * OUT_HALF];
    __shared__ float sWb[A_W * OUT_HALF];
    __shared__ float sba[OUT_HALF];
    __shared__ float sbb[OUT_HALF];
    for (int t = threadIdx.x; t < A_W * OUT_HALF; t += 256) {
        sWa[t] = Wa[t];
        sWb[t] = Wb[t];
    }
    if (BR && threadIdx.x < OUT_HALF) {
        sba[threadIdx.x] = ba[threadIdx.x];
        sbb[threadIdx.x] = bb[threadIdx.x];
    }
    __syncthreads();
    constexpr int TPN = OUT_HALF / 2;            // threads per node
    int idx = blockIdx.x * 256 + threadIdx.x;    // exact grid: N*TPN
    int n = idx / TPN;
    int q = idx % TPN;
    bool isB = (q * 4) >= OUT_HALF;
    int dd = q * 4 - (isB ? OUT_HALF : 0);
    const float* sW = isB ? sWb : sWa;
    int ko = isB ? B_OFF : A_OFF;
    float4 acc;
    if (BR) {
        const float* bp = isB ? (sbb + dd) : (sba + dd);
        acc = make_float4(bp[0], bp[1], bp[2], bp[3]);
    } else {
        acc = make_float4(0.f, 0.f, 0.f, 0.f);
    }
    const float* row = in + (size_t)n * IN_W + ko;
    #pragma unroll
    for (int k = 0; k < A_W; ++k) {
        float r = row[k];
        float4 wv = *(const float4*)&sW[k * OUT_HALF + dd];
        acc.x = fmaf(r, wv.x, acc.x);
        acc.y = fmaf(r, wv.y, acc.y);
        acc.z = fmaf(r, wv.z, acc.z);
        acc.w = fmaf(r, wv.w, acc.w);
    }
    if (BR) {
        acc.x = fmaxf(acc.x, 0.f); acc.y = fmaxf(acc.y, 0.f);
        acc.z = fmaxf(acc.z, 0.f); acc.w = fmaxf(acc.w, 0.f);
    }
    if (DS) {
        float dn = dinv[n];
        acc.x *= dn; acc.y *= dn; acc.z *= dn; acc.w *= dn;
    }
    if (OB) {
        ((uint2*)out)[idx] = make_uint2(pack2(acc.x, acc.y), pack2(acc.z, acc.w));
    } else {
        ((float4*)out)[idx] = acc;
    }
}

// ---------------- decode: sigmoid(z @ Wfc + bfc) ----------------
__global__ void __launch_bounds__(256) k_decode(const float* __restrict__ zT,
                                                const float* __restrict__ Wfc,
                                                const float* __restrict__ bfc,
                                                float* __restrict__ out) {
    int j = (blockIdx.x >> 1) * 256 + threadIdx.x;
    int gh = (blockIdx.x & 1) * 32;            // graph-half base
    const float* zp = zT + gh;                 // uniform pointer
    float bias = bfc[j];
    float acc[32];
    #pragma unroll
    for (int g = 0; g < 32; ++g) acc[g] = bias;
    #pragma unroll 8
    for (int k = 0; k < 64; ++k) {
        float w = Wfc[(size_t)k * 160000 + j];
        #pragma unroll
        for (int g = 0; g < 32; ++g)
            acc[g] = fmaf(zp[k * 64 + g], w, acc[g]);
    }
    #pragma unroll
    for (int g = 0; g < 32; ++g) {
        float s = 1.0f / (1.0f + __expf(-acc[g]));
        out[(size_t)(gh + g) * 160000 + j] = s;
    }
}

extern "C" void kernel_launch(void* const* d_in, const int* in_sizes, int n_in,
                              void* d_out, int out_size, void* d_ws, size_t ws_size,
                              hipStream_t stream) {
    const float* x     = (const float*)d_in[0];
    const int*   ei    = (const int*)d_in[1];
    const int*   batch = (const int*)d_in[2];
    const float *W1m = (const float*)d_in[3],  *b1m = (const float*)d_in[4];
    const float *W2m = (const float*)d_in[5],  *b2m = (const float*)d_in[6];
    const float *W3m = (const float*)d_in[7],  *b3m = (const float*)d_in[8];
    const float *W1l = (const float*)d_in[9],  *b1l = (const float*)d_in[10];
    const float *W2l = (const float*)d_in[11], *b2l = (const float*)d_in[12];
    const float *W3l = (const float*)d_in[13], *b3l = (const float*)d_in[14];
    const float *Wfc = (const float*)d_in[15], *bfc = (const float*)d_in[16];
    const float *eps = (const float*)d_in[17];

    const int* srcv = ei;
    const int* dstv = ei + N_EDGES;

    char* w = (char*)d_ws;
    auto alloc = [&](size_t bytes) -> char* {
        char* p = w;
        w += (bytes + 255) & ~(size_t)255;
        return p;
    };
    int*   gbase  = (int*)  alloc((size_t)NB * 4);
    int*   gcursor= (int*)  alloc((size_t)NB * 4);
    int*   rowptr = (int*)  alloc((size_t)(N_NODES + 1) * 4);
    float* dinv   = (float*)alloc((size_t)N_NODES * 4);
    float* zbuf   = (float*)alloc((size_t)N_GRAPHS * 64 * 4);
    // Arena (76.8 MB) in floats:
    //   A  [0,64N):    fixed-stride bins (CSR phase, 16 MB) -> dense1 out bf16
    //                  -> dead after gather1 -> pool partials during k_gd3/poolF
    //   B  [64N,128N): gather1 out bf16 h1 (32 dims), input to k_gd2
    //   csr[128N,160N)
    //   B2 [160N,192N): k_gd2 out bf16 (64 dims), input to k_gd3
    float* arena = (float*)alloc((size_t)N_NODES * 192 * 4);
    float* A   = arena;
    float* B   = arena + (size_t)N_NODES * 64;
    int*   csr = (int*)(arena + (size_t)N_NODES * 128);
    float* B2  = arena + (size_t)N_NODES * 160;
    int*   bins  = (int*)A;                         // [NB][MAXBKT] (CSR phase only)
    float* part0 = A;                               // [NBLK3][128]
    float* part1 = A + (size_t)NBLK3 * 128;         // [NBLK3][128]
    int*   pg0   = (int*)(A + (size_t)2 * NBLK3 * 128);
    int*   pg1   = pg0 + NBLK3;

    float* out    = (float*)d_out;
    float* out_mu = out + 10240000;
    float* out_lv = out + 10240000 + 4096;

    hipMemsetAsync(gcursor, 0, (size_t)NB * 4, stream);

    // ---- CSR build (binA-first, no count pass) ----
    k_binA<<<NCHUNK, 512, 0, stream>>>(srcv, dstv, gcursor, bins);
    k_scanB2<<<1, 512, 0, stream>>>(gcursor, gbase, rowptr);
    k_passB<<<NB, 512, 0, stream>>>(gbase, bins, csr, rowptr, dinv);

    // ---- L1: dense -> dinv*xW bf16; gather w32 -> dinv*relu(...) bf16 ----
    k_dense4<64, 16, 0, 64, 0, false, true, true><<<N_NODES * 8 / 256, 256, 0, stream>>>(
        x, W1m, b1m, W1l, b1l, dinv, A);
    k_gatherB<5, true, true, true><<<(N_NODES + 63) / 64, 256, 0, stream>>>(
        rowptr, csr, (const unsigned*)A, dinv, b1m, b1l, B);

    // ---- L2 fused: gather w32 + dense 16->32 x2 -> B2 bf16 prescaled ----
    k_gd2<<<(N_NODES + 63) / 64, 256, 0, stream>>>(
        rowptr, csr, (const unsigned*)B, dinv, W2m, b2m, W2l, b2l, (unsigned*)B2);

    // ---- L3 fused (256 thr / 32 nodes, proven): gather w64 + dense + pool partials ----
    k_gd3<<<NBLK3, 256, 0, stream>>>(
        rowptr, csr, (const unsigned*)B2, dinv, W3m, b3m, W3l, b3l, batch,
        part0, part1, pg0, pg1);

    // ---- pool reduce + reparameterize (fused) ----
    k_poolF<<<N_GRAPHS, 128, 0, stream>>>(part0, part1, pg0, pg1, batch, eps,
                                          zbuf, out_mu, out_lv);

    // ---- decode ----
    k_decode<<<1250, 256, 0, stream>>>(zbuf, Wfc, bfc, out);
}